// Round 5
// baseline (8208.498 us; speedup 1.0000x reference)
//
#include <hip/hip_runtime.h>
#include <hip/hip_bf16.h>
#include <cstddef>
#include <cstdint>

#define B     64
#define S     256
#define E     640
#define H     512
#define TSTEPS (S - 1)       // 255
#define ZDIM  4096
#define KT    64
#define HS    (B * H)        // elems per state cell (32768)
#define PBLK  128            // persistent blocks
#define CELL64 8192          // u64 units per h cell (64*512*2B / 8)

typedef __attribute__((ext_vector_type(8)))  __bf16 bf16x8;
typedef __attribute__((ext_vector_type(16))) float  f32x16;
typedef unsigned long long ull;

__device__ __forceinline__ float sigf(float x) { return 1.0f / (1.0f + __expf(-x)); }
__device__ __forceinline__ float tanhfast(float x) { return 1.0f - 2.0f / (__expf(2.0f * x) + 1.0f); }

__device__ __forceinline__ unsigned short f2bf(float f) {
    union { float f; unsigned u; } x; x.f = f;
    unsigned r = x.u + 0x7fffu + ((x.u >> 16) & 1u);   // RNE
    return (unsigned short)(r >> 16);
}
__device__ __forceinline__ float bf2f(unsigned short u) {
    union { unsigned u; float f; } x; x.u = ((unsigned)u) << 16;
    return x.f;
}

__device__ __forceinline__ bf16x8 mk8(ull lo, ull hi) {
    union { ulonglong2 u; bf16x8 v; } x;
    x.u.x = lo; x.u.y = hi;
    return x.v;
}

#define HLOAD64(p)     __hip_atomic_load((p), __ATOMIC_RELAXED, __HIP_MEMORY_SCOPE_AGENT)
#define HSTORE64(p, v) __hip_atomic_store((p), (v), __ATOMIC_RELAXED, __HIP_MEMORY_SCOPE_AGENT)

// ---------------------------------------------------------------------------
// Prep kernels
// ---------------------------------------------------------------------------
__global__ __launch_bounds__(256) void conv_x_kernel(
    const float* __restrict__ in, unsigned short* __restrict__ out, int n8)
{
    int i = blockIdx.x * 256 + threadIdx.x;
    if (i >= n8) return;
    const float4* p = (const float4*)(in + (size_t)i * 8);
    float4 a = p[0], b = p[1];
    unsigned short* o = out + (size_t)i * 8;
    o[0] = f2bf(a.x); o[1] = f2bf(a.y); o[2] = f2bf(a.z); o[3] = f2bf(a.w);
    o[4] = f2bf(b.x); o[5] = f2bf(b.y); o[6] = f2bf(b.z); o[7] = f2bf(b.w);
}

// out[d][n][k] = in[d][(n&3)*512 + (n>>2)][k], bf16  (gate-minor packing)
__global__ __launch_bounds__(256) void repack_w_kernel(
    const float* __restrict__ in, unsigned short* __restrict__ out, int K)
{
    int kc = K / 8;
    int i = blockIdx.x * 256 + threadIdx.x;
    if (i >= 2 * 2048 * kc) return;
    int k8 = i % kc;
    int n  = (i / kc) & 2047;
    int d  = i / (kc * 2048);
    int srow = (n & 3) * 512 + (n >> 2);
    const float* src = in + ((size_t)d * 2048 + srow) * K + (size_t)k8 * 8;
    unsigned short* dst = out + ((size_t)d * 2048 + n) * K + (size_t)k8 * 8;
    #pragma unroll
    for (int q = 0; q < 8; ++q) dst[q] = f2bf(src[q]);
}

__global__ __launch_bounds__(256) void pack_bias_kernel(
    const float* __restrict__ bih, const float* __restrict__ bhh, float* __restrict__ out)
{
    int i = blockIdx.x * 256 + threadIdx.x;   // 4096
    if (i >= 4096) return;
    int d = i >> 11, n = i & 2047;
    int s = d * 2048 + (n & 3) * 512 + (n >> 2);
    out[i] = bih[s] + bhh[s];
}

// ---------------------------------------------------------------------------
// Monotone ready-counter wait (tid0 only; caller does __syncthreads after)
// ---------------------------------------------------------------------------
__device__ __forceinline__ void wait_ge(unsigned* p, unsigned tgt) {
    while (__hip_atomic_load(p, __ATOMIC_RELAXED, __HIP_MEMORY_SCOPE_AGENT) < tgt) {}
}

// ---------------------------------------------------------------------------
// Batched coherent A-loads (h state) + MFMA consumers
// ---------------------------------------------------------------------------
__device__ __forceinline__ void issue8(ull* bf, const ull* hp, int b8) {
#pragma unroll
    for (int j = 0; j < 8; ++j) {
        bf[2*j]   = HLOAD64(hp + (size_t)(b8 + j) * 4);
        bf[2*j+1] = HLOAD64(hp + (size_t)(b8 + j) * 4 + 1);
    }
}

__device__ __forceinline__ void consume8_lds(const ull* bf, int b8,
    const char* ldsrow, int rotofs, int wrapB, f32x16& a0, f32x16& a1)
{
#pragma unroll
    for (int j = 0; j < 8; ++j) {
        bf16x8 a = mk8(bf[2*j], bf[2*j+1]);
        int o = (b8 + j) * 32 + rotofs;
        o -= (o >= wrapB) ? wrapB : 0;
        bf16x8 b = *(const bf16x8*)(ldsrow + o);
        if ((b8 + j) & 1) a1 = __builtin_amdgcn_mfma_f32_32x32x16_bf16(a, b, a1, 0, 0, 0);
        else              a0 = __builtin_amdgcn_mfma_f32_32x32x16_bf16(a, b, a0, 0, 0, 0);
    }
}

__device__ __forceinline__ void consume8_glb(const ull* bf, int b8,
    const unsigned short* wp, f32x16& a0, f32x16& a1)
{
#pragma unroll
    for (int j = 0; j < 8; ++j) {
        bf16x8 a = mk8(bf[2*j], bf[2*j+1]);
        bf16x8 b = *(const bf16x8*)(wp + (size_t)(b8 + j) * 16);
        if ((b8 + j) & 1) a1 = __builtin_amdgcn_mfma_f32_32x32x16_bf16(a, b, a1, 0, 0, 0);
        else              a0 = __builtin_amdgcn_mfma_f32_32x32x16_bf16(a, b, a0, 0, 0, 0);
    }
}

// full K=512 h-cell segment, B from LDS (3-deep rotating load batches)
__device__ __forceinline__ void hcell_lds(const ull* hp, const char* ldsrow,
    int rotofs, int wrapB, f32x16& a0, f32x16& a1)
{
    ull b0[16], b1[16], b2[16];
    issue8(b0, hp, 0); issue8(b1, hp, 8); issue8(b2, hp, 16);
    consume8_lds(b0, 0,  ldsrow, rotofs, wrapB, a0, a1);
    issue8(b0, hp, 24);
    consume8_lds(b1, 8,  ldsrow, rotofs, wrapB, a0, a1);
    consume8_lds(b2, 16, ldsrow, rotofs, wrapB, a0, a1);
    consume8_lds(b0, 24, ldsrow, rotofs, wrapB, a0, a1);
}

// full K=512 h-cell segment, B streamed from global (L2-hot weights)
__device__ __forceinline__ void hcell_glb(const ull* hp, const unsigned short* wp,
    f32x16& a0, f32x16& a1)
{
    ull b0[16], b1[16], b2[16];
    issue8(b0, hp, 0); issue8(b1, hp, 8); issue8(b2, hp, 16);
    consume8_glb(b0, 0,  wp, a0, a1);
    issue8(b0, hp, 24);
    consume8_glb(b1, 8,  wp, a0, a1);
    consume8_glb(b2, 16, wp, a0, a1);
    consume8_glb(b0, 24, wp, a0, a1);
}

// ---------------------------------------------------------------------------
// Activation + c-in-registers + packed coherent h store
// ---------------------------------------------------------------------------
__device__ __forceinline__ void act_store(
    const f32x16& a0, const f32x16& a1, int unitg, int wm, int l,
    float* creg, ull* hq_cell)
{
    const int g  = l & 3;
    const int hi = l >> 5;
    float gi[4], gf[4], gg[4], go[4];
#pragma unroll
    for (int r = 0; r < 16; ++r) {
        float v0 = a0[r] + a1[r];
        float v1 = __shfl_xor(v0, 1);
        float v2 = __shfl_xor(v0, 2);
        float v3 = __shfl_xor(v0, 3);
        float pv[4] = {v0, v1, v2, v3};
        const int rg = r & 3, q = r >> 2;
        if (g == rg) { gi[q] = pv[rg^0]; gf[q] = pv[rg^1]; gg[q] = pv[rg^2]; go[q] = pv[rg^3]; }
    }
    const int ubase = unitg & ~3;
#pragma unroll
    for (int q = 0; q < 4; ++q) {
        int row = 32*wm + g + 8*q + 4*hi;
        float cold = creg[q];
        float cnew = sigf(gf[q]) * cold + sigf(gi[q]) * tanhfast(gg[q]);
        float hnew = sigf(go[q]) * tanhfast(cnew);
        creg[q] = cnew;
        unsigned m  = f2bf(hnew);
        unsigned o1 = __shfl_xor(m, 4);
        unsigned d0 = (unitg & 1) ? ((m << 16) | o1) : ((o1 << 16) | m);
        unsigned o2 = __shfl_xor(d0, 8);
        ull q64 = (unitg & 2) ? (((ull)d0 << 32) | (ull)o2) : (((ull)o2 << 32) | (ull)d0);
        if ((l & 12) == 0)
            HSTORE64(hq_cell + (size_t)row * 128 + (ubase >> 2), q64);
    }
}

// ---------------------------------------------------------------------------
// Persistent recurrence kernel. 128 blocks x 256 threads, 144KB dynamic LDS.
// bid<64: L0; else L1. Block tile: 64 batch rows x 64 packed cols.
// Sync: 4 monotone per-cell ready counters; no global barrier.
//   R[c] totals: L0 cells (d=0,1) +32/iter for iters 0..254;
//                L1 cells (2+d)  +32/iter for iters 1..255.
//   Self-gating proof: at the first time R[c] >= 32k, no producer of c can
//   have completed iter k (its wait needed R[c] >= 32k earlier), so all 32
//   completed exactly iters < k  =>  R[c] >= 32k  <=>  iter k-1 data visible.
//   Anti-WAR: 3-buffer rotation (write (k+1)%3, read k%3); buf (k+1)%3 was
//   last read at iter k-2, protected by waits on counters of those readers.
// ---------------------------------------------------------------------------
__global__ __launch_bounds__(256, 1) void persist_kernel(
    const unsigned short* __restrict__ xb,
    const unsigned short* __restrict__ w0p,
    const unsigned short* __restrict__ wh0p,
    const unsigned short* __restrict__ w1p,
    const unsigned short* __restrict__ wh1p,
    const float* __restrict__ b0p,
    const float* __restrict__ b1p,
    unsigned short* __restrict__ hbuf,   // (3,4,64,512) bf16, coherent-accessed
    float* __restrict__ cbuf,            // (4,64,512) f32 (final only)
    unsigned* __restrict__ ready)        // 4 counters, 256B apart (u32 idx c*64)
{
    extern __shared__ __align__(16) char lds[];
    const int tid = threadIdx.x;
    const int l   = tid & 63;
    const int w   = tid >> 6;
    const int wm  = w & 1, wn = w >> 1;
    const int bid = blockIdx.x;
    const bool isL1 = bid >= 64;
    const int g2 = bid & 63;
    const int d  = g2 >> 5;
    const int n0 = (g2 & 31) * 64;
    const int lrow  = wn * 32 + (l & 31);    // weight row (output col), local
    const int khalf = l >> 5;
    const int arow  = wm * 32 + (l & 31);    // batch row for A operand
    const int HHOFF = 64 * 1280;             // L0 hh region offset

    // ---- stage weights into LDS (16B-per-row rotate, exact strides) --------
    if (!isL1) {
        for (int idx = tid; idx < 64 * 80; idx += 256) {   // ih: 64 x 640
            int r = idx / 80, k8 = idx % 80;
            bf16x8 v = *(const bf16x8*)(w0p + ((size_t)d*2048 + n0 + r)*640 + (size_t)k8*8);
            int o = k8*16 + r*16; o -= (o >= 1280) ? 1280 : 0;
            *(bf16x8*)(lds + r*1280 + o) = v;
        }
        for (int idx = tid; idx < 64 * 64; idx += 256) {   // hh: 64 x 512
            int r = idx / 64, k8 = idx % 64;
            bf16x8 v = *(const bf16x8*)(wh0p + ((size_t)d*2048 + n0 + r)*512 + (size_t)k8*8);
            int o = k8*16 + r*16; o -= (o >= 1024) ? 1024 : 0;
            *(bf16x8*)(lds + HHOFF + r*1024 + o) = v;
        }
    } else {
        for (int idx = tid; idx < 64 * 128; idx += 256) {  // ih: 64 x 1024
            int r = idx / 128, k8 = idx % 128;
            bf16x8 v = *(const bf16x8*)(w1p + ((size_t)d*2048 + n0 + r)*1024 + (size_t)k8*8);
            int o = k8*16 + r*16; o -= (o >= 2048) ? 2048 : 0;
            *(bf16x8*)(lds + r*2048 + o) = v;
        }
    }
    __syncthreads();

    const int IHB = isL1 ? 2048 : 1280;
    const float bias = (isL1 ? b1p : b0p)[d*2048 + n0 + lrow];
    const char* ldsrow_ih = lds + (size_t)lrow * IHB;
    const char* ldsrow_hh = lds + HHOFF + (size_t)lrow * 1024;
    const int rot = lrow * 16 + khalf * 16;
    const int unitg = ((n0 + lrow) >> 2);
    float creg[4] = {0.f, 0.f, 0.f, 0.f};
    const ull* hb = (const ull*)hbuf;
    ull*       hw = (ull*)hbuf;
    const unsigned short* whh1_lane =
        wh1p + ((size_t)d*2048 + n0 + lrow) * 512 + khalf * 8;
    const int mycell = isL1 ? (2 + d) : d;

    for (int k = 0; k <= TSTEPS; ++k) {
        const int rbuf = k % 3, wbuf = (k + 1) % 3;
        const size_t rb = (size_t)rbuf * 4 * CELL64;
        if (!isL1) {
            if (k < TSTEPS) {
                f32x16 a0, a1;
#pragma unroll
                for (int r = 0; r < 16; ++r) { a0[r] = bias; a1[r] = 0.f; }
                // x segment (K=640) — independent of recurrence, off critical path
                const unsigned short* Ax = xb + (size_t)k*B*E + (size_t)arow*E + khalf*8;
#pragma unroll 8
                for (int k0 = 0; k0 < E; k0 += 16) {
                    bf16x8 a = *(const bf16x8*)(Ax + k0);
                    int o = k0*2 + rot; o -= (o >= 1280) ? 1280 : 0;
                    bf16x8 b = *(const bf16x8*)(ldsrow_ih + o);
                    if ((k0 >> 4) & 1) a1 = __builtin_amdgcn_mfma_f32_32x32x16_bf16(a, b, a1, 0, 0, 0);
                    else               a0 = __builtin_amdgcn_mfma_f32_32x32x16_bf16(a, b, a0, 0, 0, 0);
                }
                // wait: own cell data (RAW) + L1 readers of the buf we'll write (WAR)
                if (tid == 0) {
                    if (k >= 1) wait_ge(ready + d*64, 32u*(unsigned)k);
                    if (k >= 3) {
                        wait_ge(ready + 2*64, 32u*(unsigned)(k-2));
                        wait_ge(ready + 3*64, 32u*(unsigned)(k-2));
                    }
                }
                __syncthreads();
                // hidden segment (K=512) from buf rbuf cell d
                const ull* hp = hb + rb + (size_t)d*CELL64 + (size_t)arow*128 + khalf*2;
                hcell_lds(hp, ldsrow_hh, rot, 1024, a0, a1);
                act_store(a0, a1, unitg, wm, l, creg,
                          hw + (size_t)wbuf*4*CELL64 + (size_t)d*CELL64);
                asm volatile("s_waitcnt vmcnt(0)" ::: "memory");
                __syncthreads();                       // all lanes' stores acked
                if (tid == 0)
                    __hip_atomic_fetch_add(ready + mycell*64, 1u,
                                           __ATOMIC_RELAXED, __HIP_MEMORY_SCOPE_AGENT);
            }
        } else {
            if (k >= 1) {
                f32x16 a0, a1;
#pragma unroll
                for (int r = 0; r < 16; ++r) { a0[r] = bias; a1[r] = 0.f; }
                // phase A: own hidden cell (self-group; usually already ready)
                if (tid == 0 && k >= 2) wait_ge(ready + (2+d)*64, 32u*(unsigned)(k-1));
                __syncthreads();
                const ull* hp2 = hb + rb + (size_t)(2+d)*CELL64 + (size_t)arow*128 + khalf*2;
                hcell_glb(hp2, whh1_lane, a0, a1);
                // phase B: inputs from L0's cells 0,1 (buf rbuf, iter k-1 data)
                if (tid == 0) {
                    wait_ge(ready + 0*64, 32u*(unsigned)k);
                    wait_ge(ready + 1*64, 32u*(unsigned)k);
                }
                __syncthreads();
                const ull* hp0 = hb + rb + (size_t)0*CELL64 + (size_t)arow*128 + khalf*2;
                hcell_lds(hp0, ldsrow_ih, rot,        2048, a0, a1);
                const ull* hp1 = hb + rb + (size_t)1*CELL64 + (size_t)arow*128 + khalf*2;
                hcell_lds(hp1, ldsrow_ih, rot + 1024, 2048, a0, a1);
                act_store(a0, a1, unitg, wm, l, creg,
                          hw + (size_t)wbuf*4*CELL64 + (size_t)(2+d)*CELL64);
                asm volatile("s_waitcnt vmcnt(0)" ::: "memory");
                __syncthreads();
                if (tid == 0)
                    __hip_atomic_fetch_add(ready + mycell*64, 1u,
                                           __ATOMIC_RELAXED, __HIP_MEMORY_SCOPE_AGENT);
            }
        }
    }

    // final c write-out (plain stores; visible to head after kernel boundary)
    {
        float* cc = cbuf + (size_t)mycell * HS;
        const int g = l & 3, hi = l >> 5;
#pragma unroll
        for (int q = 0; q < 4; ++q) {
            int row = 32*wm + g + 8*q + 4*hi;
            cc[(size_t)row * 512 + unitg] = creg[q];
        }
    }
}

// ---------------------------------------------------------------------------
// Head. Final h: cells 0,1 in buf 0 (L0 wrote wbuf=255%3=0 at k=254);
//               cells 2,3 in buf 1 (L1 wrote wbuf=256%3=1 at k=255).
// ---------------------------------------------------------------------------
__global__ __launch_bounds__(256) void head_kernel(
    const unsigned short* __restrict__ hbuf,
    const float* __restrict__ cbuf,
    const float* __restrict__ eps,
    const float* __restrict__ Wmu,  const float* __restrict__ bmu,
    const float* __restrict__ Wvar, const float* __restrict__ bvar,
    float* __restrict__ out)
{
    const int tid = threadIdx.x;
    const int b   = tid & 63;
    const int i   = blockIdx.x * 4 + (tid >> 6);

    __shared__ float zs[KT][B + 1];

    float amu = 0.f, alv = 0.f;
    const float* wm = Wmu  + (size_t)i * ZDIM;
    const float* wv = Wvar + (size_t)i * ZDIM;

    for (int k0 = 0; k0 < ZDIM; k0 += KT) {
        __syncthreads();
        for (int idx = tid; idx < (B * KT) / 4; idx += 256) {
            int bb  = idx / (KT / 4);
            int kq4 = (idx % (KT / 4)) * 4;
            int zk  = k0 + kq4;
            int cell = zk >> 10;
            int m    = zk & 1023;
            float4 v;
            if (m < H) {
                const unsigned short* hs = hbuf
                    + (((size_t)((cell < 2) ? 0 : 1)) * 4 + cell) * HS
                    + (size_t)bb * H + m;
                v.x = bf2f(hs[0]); v.y = bf2f(hs[1]); v.z = bf2f(hs[2]); v.w = bf2f(hs[3]);
            } else {
                v = *(const float4*)(cbuf + (size_t)cell * HS + (size_t)bb * H + (m - H));
            }
            zs[kq4 + 0][bb] = v.x; zs[kq4 + 1][bb] = v.y;
            zs[kq4 + 2][bb] = v.z; zs[kq4 + 3][bb] = v.w;
        }
        __syncthreads();
        #pragma unroll
        for (int kk = 0; kk < KT; kk += 4) {
            float4 a = *(const float4*)(wm + k0 + kk);
            float4 c = *(const float4*)(wv + k0 + kk);
            float z0 = zs[kk + 0][b], z1 = zs[kk + 1][b];
            float z2 = zs[kk + 2][b], z3 = zs[kk + 3][b];
            amu += a.x * z0 + a.y * z1 + a.z * z2 + a.w * z3;
            alv += c.x * z0 + c.y * z1 + c.z * z2 + c.w * z3;
        }
    }
    float mu = amu + bmu[i];
    float lv = alv + bvar[i];
    out[(size_t)b * ZDIM + i] = mu + eps[(size_t)b * ZDIM + i] * __expf(0.5f * lv);
}

// ---------------------------------------------------------------------------
extern "C" void kernel_launch(void* const* d_in, const int* in_sizes, int n_in,
                              void* d_out, int out_size, void* d_ws, size_t ws_size,
                              hipStream_t stream) {
    const float* input = (const float*)d_in[0];
    const float* eps   = (const float*)d_in[1];
    const float* w_ih0 = (const float*)d_in[2];
    const float* w_hh0 = (const float*)d_in[3];
    const float* b_ih0 = (const float*)d_in[4];
    const float* b_hh0 = (const float*)d_in[5];
    const float* w_ih1 = (const float*)d_in[6];
    const float* w_hh1 = (const float*)d_in[7];
    const float* b_ih1 = (const float*)d_in[8];
    const float* b_hh1 = (const float*)d_in[9];
    const float* W_mu  = (const float*)d_in[10];
    const float* b_mu  = (const float*)d_in[11];
    const float* W_var = (const float*)d_in[12];
    const float* b_var = (const float*)d_in[13];
    float* out = (float*)d_out;

    uint8_t* base = (uint8_t*)d_ws;
    size_t off = 0;
    auto alloc = [&](size_t bytes) -> void* {
        void* p = base + off;
        off += (bytes + 255) & ~(size_t)255;
        return p;
    };
    unsigned short* xb   = (unsigned short*)alloc((size_t)TSTEPS * B * E * 2);
    unsigned short* w0p  = (unsigned short*)alloc((size_t)2 * 2048 * E * 2);
    unsigned short* wh0p = (unsigned short*)alloc((size_t)2 * 2048 * H * 2);
    unsigned short* w1p  = (unsigned short*)alloc((size_t)2 * 2048 * 1024 * 2);
    unsigned short* wh1p = (unsigned short*)alloc((size_t)2 * 2048 * H * 2);
    float* b0p = (float*)alloc(2 * 2048 * 4);
    float* b1p = (float*)alloc(2 * 2048 * 4);
    unsigned* ready      = (unsigned*)alloc(1024);                    // 4 x 256B
    unsigned short* hbuf = (unsigned short*)alloc((size_t)3 * 4 * HS * 2);
    float* cbuf          = (float*)alloc((size_t)4 * HS * 4);

    // zero ready + h (3 bufs) + c — contiguous region
    hipMemsetAsync(ready, 0, 1024 + (size_t)3 * 4 * HS * 2 + (size_t)4 * HS * 4, stream);

    conv_x_kernel<<<(TSTEPS * B * E / 8 + 255) / 256, 256, 0, stream>>>(input, xb, TSTEPS * B * E / 8);
    repack_w_kernel<<<(2 * 2048 * (E / 8) + 255) / 256, 256, 0, stream>>>(w_ih0, w0p, E);
    repack_w_kernel<<<(2 * 2048 * (H / 8) + 255) / 256, 256, 0, stream>>>(w_hh0, wh0p, H);
    repack_w_kernel<<<(2 * 2048 * (1024 / 8) + 255) / 256, 256, 0, stream>>>(w_ih1, w1p, 1024);
    repack_w_kernel<<<(2 * 2048 * (H / 8) + 255) / 256, 256, 0, stream>>>(w_hh1, wh1p, H);
    pack_bias_kernel<<<16, 256, 0, stream>>>(b_ih0, b_hh0, b0p);
    pack_bias_kernel<<<16, 256, 0, stream>>>(b_ih1, b_hh1, b1p);

    const size_t lds_bytes = 144 * 1024;
    hipFuncSetAttribute((const void*)persist_kernel,
                        hipFuncAttributeMaxDynamicSharedMemorySize, (int)lds_bytes);
    persist_kernel<<<PBLK, 256, lds_bytes, stream>>>(
        xb, w0p, wh0p, w1p, wh1p, b0p, b1p, hbuf, cbuf, ready);

    head_kernel<<<ZDIM / 4, 256, 0, stream>>>(hbuf, cbuf, eps, W_mu, b_mu, W_var, b_var, out);
}

// Round 6
// 4105.156 us; speedup vs baseline: 1.9996x; 1.9996x over previous
//
#include <hip/hip_runtime.h>
#include <hip/hip_bf16.h>
#include <cstddef>
#include <cstdint>

#define B     64
#define S     256
#define E     640
#define H     512
#define TSTEPS (S - 1)       // 255
#define ZDIM  4096
#define KT    64
#define HS    (B * H)        // elems per state cell (32768)
#define PBLK  128            // persistent blocks
#define CELL64 8192          // u64 units per h cell (64*512*2B / 8)

typedef __attribute__((ext_vector_type(8)))  __bf16 bf16x8;
typedef __attribute__((ext_vector_type(16))) float  f32x16;
typedef unsigned long long ull;

__device__ __forceinline__ float sigf(float x) { return 1.0f / (1.0f + __expf(-x)); }
__device__ __forceinline__ float tanhfast(float x) { return 1.0f - 2.0f / (__expf(2.0f * x) + 1.0f); }

__device__ __forceinline__ unsigned short f2bf(float f) {
    union { float f; unsigned u; } x; x.f = f;
    unsigned r = x.u + 0x7fffu + ((x.u >> 16) & 1u);   // RNE
    return (unsigned short)(r >> 16);
}
__device__ __forceinline__ float bf2f(unsigned short u) {
    union { unsigned u; float f; } x; x.u = ((unsigned)u) << 16;
    return x.f;
}

__device__ __forceinline__ bf16x8 mk8(ull lo, ull hi) {
    union { ulonglong2 u; bf16x8 v; } x;
    x.u.x = lo; x.u.y = hi;
    return x.v;
}

#define HLOAD64(p)     __hip_atomic_load((p), __ATOMIC_RELAXED, __HIP_MEMORY_SCOPE_AGENT)
#define HSTORE64(p, v) __hip_atomic_store((p), (v), __ATOMIC_RELAXED, __HIP_MEMORY_SCOPE_AGENT)

// h-cell fragment layout (u64 granules):
//   idx = wm*4096 + m*128 + khalf*64 + plane*32 + row   (wm,row: 32-row half;
//   granule = h[32*wm+row][k = m*16 + khalf*8 + plane*4 + 0..3], k ascending LE)
// Consumer lane l, mfma m: lo = idx(m, khalf=l>>5, plane=0, row=l&31), hi = lo+32.
// => 64 lanes read 64 consecutive u64s: fully coalesced.

// ---------------------------------------------------------------------------
// Prep kernels
// ---------------------------------------------------------------------------
__global__ __launch_bounds__(256) void conv_x_kernel(
    const float* __restrict__ in, unsigned short* __restrict__ out, int n8)
{
    int i = blockIdx.x * 256 + threadIdx.x;
    if (i >= n8) return;
    const float4* p = (const float4*)(in + (size_t)i * 8);
    float4 a = p[0], b = p[1];
    unsigned short* o = out + (size_t)i * 8;
    o[0] = f2bf(a.x); o[1] = f2bf(a.y); o[2] = f2bf(a.z); o[3] = f2bf(a.w);
    o[4] = f2bf(b.x); o[5] = f2bf(b.y); o[6] = f2bf(b.z); o[7] = f2bf(b.w);
}

// out[d][n][k] = in[d][(n&3)*512 + (n>>2)][k], bf16  (gate-minor packing)
__global__ __launch_bounds__(256) void repack_w_kernel(
    const float* __restrict__ in, unsigned short* __restrict__ out, int K)
{
    int kc = K / 8;
    int i = blockIdx.x * 256 + threadIdx.x;
    if (i >= 2 * 2048 * kc) return;
    int k8 = i % kc;
    int n  = (i / kc) & 2047;
    int d  = i / (kc * 2048);
    int srow = (n & 3) * 512 + (n >> 2);
    const float* src = in + ((size_t)d * 2048 + srow) * K + (size_t)k8 * 8;
    unsigned short* dst = out + ((size_t)d * 2048 + n) * K + (size_t)k8 * 8;
    #pragma unroll
    for (int q = 0; q < 8; ++q) dst[q] = f2bf(src[q]);
}

__global__ __launch_bounds__(256) void pack_bias_kernel(
    const float* __restrict__ bih, const float* __restrict__ bhh, float* __restrict__ out)
{
    int i = blockIdx.x * 256 + threadIdx.x;   // 4096
    if (i >= 4096) return;
    int d = i >> 11, n = i & 2047;
    int s = d * 2048 + (n & 3) * 512 + (n >> 2);
    out[i] = bih[s] + bhh[s];
}

// ---------------------------------------------------------------------------
// Monotone ready-counter wait (tid0 only; caller does __syncthreads after)
// ---------------------------------------------------------------------------
__device__ __forceinline__ void wait_ge(unsigned* p, unsigned tgt) {
    while (__hip_atomic_load(p, __ATOMIC_RELAXED, __HIP_MEMORY_SCOPE_AGENT) < tgt) {}
}

// ---------------------------------------------------------------------------
// Coalesced coherent A-loads (fragment-order h) + MFMA consumers
// hp is pre-offset: cell_u64 + wm*4096 + (l>>5)*64 + (l&31)
// ---------------------------------------------------------------------------
__device__ __forceinline__ void issueM(ull* bf, const ull* hp, int mb) {
#pragma unroll
    for (int j = 0; j < 8; ++j) {
        bf[2*j]   = HLOAD64(hp + (size_t)(mb + j) * 128);
        bf[2*j+1] = HLOAD64(hp + (size_t)(mb + j) * 128 + 32);
    }
}

__device__ __forceinline__ void consume8_lds(const ull* bf, int mb,
    const char* ldsrow, int rotofs, int wrapB, f32x16& a0, f32x16& a1)
{
#pragma unroll
    for (int j = 0; j < 8; ++j) {
        bf16x8 a = mk8(bf[2*j], bf[2*j+1]);
        int o = (mb + j) * 32 + rotofs;
        o -= (o >= wrapB) ? wrapB : 0;
        bf16x8 b = *(const bf16x8*)(ldsrow + o);
        if ((mb + j) & 1) a1 = __builtin_amdgcn_mfma_f32_32x32x16_bf16(a, b, a1, 0, 0, 0);
        else              a0 = __builtin_amdgcn_mfma_f32_32x32x16_bf16(a, b, a0, 0, 0, 0);
    }
}

__device__ __forceinline__ void consume8_glb(const ull* bf, int mb,
    const unsigned short* wp, f32x16& a0, f32x16& a1)
{
#pragma unroll
    for (int j = 0; j < 8; ++j) {
        bf16x8 a = mk8(bf[2*j], bf[2*j+1]);
        bf16x8 b = *(const bf16x8*)(wp + (size_t)(mb + j) * 16);
        if ((mb + j) & 1) a1 = __builtin_amdgcn_mfma_f32_32x32x16_bf16(a, b, a1, 0, 0, 0);
        else              a0 = __builtin_amdgcn_mfma_f32_32x32x16_bf16(a, b, a0, 0, 0, 0);
    }
}

// full K=512 h-cell segment, B from LDS (3-deep rotating load batches)
__device__ __forceinline__ void hcell_lds(const ull* hp, const char* ldsrow,
    int rotofs, int wrapB, f32x16& a0, f32x16& a1)
{
    ull b0[16], b1[16], b2[16];
    issueM(b0, hp, 0); issueM(b1, hp, 8); issueM(b2, hp, 16);
    consume8_lds(b0, 0,  ldsrow, rotofs, wrapB, a0, a1);
    issueM(b0, hp, 24);
    consume8_lds(b1, 8,  ldsrow, rotofs, wrapB, a0, a1);
    consume8_lds(b2, 16, ldsrow, rotofs, wrapB, a0, a1);
    consume8_lds(b0, 24, ldsrow, rotofs, wrapB, a0, a1);
}

// full K=512 h-cell segment, B streamed from global (L2-hot weights)
__device__ __forceinline__ void hcell_glb(const ull* hp, const unsigned short* wp,
    f32x16& a0, f32x16& a1)
{
    ull b0[16], b1[16], b2[16];
    issueM(b0, hp, 0); issueM(b1, hp, 8); issueM(b2, hp, 16);
    consume8_glb(b0, 0,  wp, a0, a1);
    issueM(b0, hp, 24);
    consume8_glb(b1, 8,  wp, a0, a1);
    consume8_glb(b2, 16, wp, a0, a1);
    consume8_glb(b0, 24, wp, a0, a1);
}

// ---------------------------------------------------------------------------
// Activation + c/h-in-registers + coalesced fragment-order h store
// ---------------------------------------------------------------------------
__device__ __forceinline__ void act_store(
    const f32x16& a0, const f32x16& a1, int unitg, int wm, int l,
    float* creg, float* hreg, ull* hq_cell)
{
    const int g  = l & 3;
    const int hi = l >> 5;
    float gi[4], gf[4], gg[4], go[4];
#pragma unroll
    for (int r = 0; r < 16; ++r) {
        float v0 = a0[r] + a1[r];
        float v1 = __shfl_xor(v0, 1);
        float v2 = __shfl_xor(v0, 2);
        float v3 = __shfl_xor(v0, 3);
        float pv[4] = {v0, v1, v2, v3};
        const int rg = r & 3, q = r >> 2;
        if (g == rg) { gi[q] = pv[rg^0]; gf[q] = pv[rg^1]; gg[q] = pv[rg^2]; go[q] = pv[rg^3]; }
    }
    const int ubase = unitg & ~3;
    ull* dst = hq_cell + wm*4096 + (ubase >> 4)*128 + ((ubase >> 3) & 1)*64
                       + ((ubase >> 2) & 1)*32;
#pragma unroll
    for (int q = 0; q < 4; ++q) {
        int rl = g + 8*q + 4*hi;               // row within 32-row half
        float cold = creg[q];
        float cnew = sigf(gf[q]) * cold + sigf(gi[q]) * tanhfast(gg[q]);
        float hnew = sigf(go[q]) * tanhfast(cnew);
        creg[q] = cnew;
        hreg[q] = hnew;
        unsigned m  = f2bf(hnew);
        unsigned o1 = __shfl_xor(m, 4);
        unsigned d0 = (unitg & 1) ? ((m << 16) | o1) : ((o1 << 16) | m);
        unsigned o2 = __shfl_xor(d0, 8);
        ull q64 = (unitg & 2) ? (((ull)d0 << 32) | (ull)o2) : (((ull)o2 << 32) | (ull)d0);
        if ((l & 12) == 0)
            HSTORE64(dst + rl, q64);
    }
}

// ---------------------------------------------------------------------------
// Persistent recurrence kernel. 128 blocks x 256 threads, 144KB dynamic LDS.
// bid<64: L0; else L1. Block tile: 64 batch rows x 64 packed cols.
// Sync: 4 monotone per-cell ready counters (proof in r4/r5 comments).
// h exchanged in MFMA-fragment order => all coherent traffic coalesced.
// ---------------------------------------------------------------------------
__global__ __launch_bounds__(256, 1) void persist_kernel(
    const unsigned short* __restrict__ xb,
    const unsigned short* __restrict__ w0p,
    const unsigned short* __restrict__ wh0p,
    const unsigned short* __restrict__ w1p,
    const unsigned short* __restrict__ wh1p,
    const float* __restrict__ b0p,
    const float* __restrict__ b1p,
    unsigned short* __restrict__ hbuf,   // (3 bufs,4 cells) fragment-order bf16
    float* __restrict__ cbuf,            // (4,64,512) f32 plain (final only)
    unsigned short* __restrict__ hplain, // (4,64,512) bf16 plain (final only)
    unsigned* __restrict__ ready)        // 4 counters, 256B apart (u32 idx c*64)
{
    extern __shared__ __align__(16) char lds[];
    const int tid = threadIdx.x;
    const int l   = tid & 63;
    const int w   = tid >> 6;
    const int wm  = w & 1, wn = w >> 1;
    const int bid = blockIdx.x;
    const bool isL1 = bid >= 64;
    const int g2 = bid & 63;
    const int d  = g2 >> 5;
    const int n0 = (g2 & 31) * 64;
    const int lrow  = wn * 32 + (l & 31);    // weight row (output col), local
    const int khalf = l >> 5;
    const int HHOFF = 64 * 1280;             // L0 hh region offset

    // ---- stage weights into LDS (16B-per-row rotate, exact strides) --------
    if (!isL1) {
        for (int idx = tid; idx < 64 * 80; idx += 256) {   // ih: 64 x 640
            int r = idx / 80, k8 = idx % 80;
            bf16x8 v = *(const bf16x8*)(w0p + ((size_t)d*2048 + n0 + r)*640 + (size_t)k8*8);
            int o = k8*16 + r*16; o -= (o >= 1280) ? 1280 : 0;
            *(bf16x8*)(lds + r*1280 + o) = v;
        }
        for (int idx = tid; idx < 64 * 64; idx += 256) {   // hh: 64 x 512
            int r = idx / 64, k8 = idx % 64;
            bf16x8 v = *(const bf16x8*)(wh0p + ((size_t)d*2048 + n0 + r)*512 + (size_t)k8*8);
            int o = k8*16 + r*16; o -= (o >= 1024) ? 1024 : 0;
            *(bf16x8*)(lds + HHOFF + r*1024 + o) = v;
        }
    } else {
        for (int idx = tid; idx < 64 * 128; idx += 256) {  // ih: 64 x 1024
            int r = idx / 128, k8 = idx % 128;
            bf16x8 v = *(const bf16x8*)(w1p + ((size_t)d*2048 + n0 + r)*1024 + (size_t)k8*8);
            int o = k8*16 + r*16; o -= (o >= 2048) ? 2048 : 0;
            *(bf16x8*)(lds + r*2048 + o) = v;
        }
    }
    __syncthreads();

    const int IHB = isL1 ? 2048 : 1280;
    const float bias = (isL1 ? b1p : b0p)[d*2048 + n0 + lrow];
    const char* ldsrow_ih = lds + (size_t)lrow * IHB;
    const char* ldsrow_hh = lds + HHOFF + (size_t)lrow * 1024;
    const int rot = lrow * 16 + khalf * 16;
    const int unitg = ((n0 + lrow) >> 2);
    const int hoff  = wm*4096 + khalf*64 + (l & 31);   // consumer A-frag offset
    const int arow  = wm * 32 + (l & 31);              // batch row (x segment)
    float creg[4] = {0.f, 0.f, 0.f, 0.f};
    float hreg[4] = {0.f, 0.f, 0.f, 0.f};
    const ull* hb = (const ull*)hbuf;
    ull*       hw = (ull*)hbuf;
    const unsigned short* whh1_lane =
        wh1p + ((size_t)d*2048 + n0 + lrow) * 512 + khalf * 8;
    const int mycell = isL1 ? (2 + d) : d;

    for (int k = 0; k <= TSTEPS; ++k) {
        const int rbuf = k % 3, wbuf = (k + 1) % 3;
        const size_t rb = (size_t)rbuf * 4 * CELL64;
        if (!isL1) {
            if (k < TSTEPS) {
                f32x16 a0, a1;
#pragma unroll
                for (int r = 0; r < 16; ++r) { a0[r] = bias; a1[r] = 0.f; }
                // x segment (K=640) — independent of recurrence, off critical path
                const unsigned short* Ax = xb + (size_t)k*B*E + (size_t)arow*E + khalf*8;
#pragma unroll 8
                for (int k0 = 0; k0 < E; k0 += 16) {
                    bf16x8 a = *(const bf16x8*)(Ax + k0);
                    int o = k0*2 + rot; o -= (o >= 1280) ? 1280 : 0;
                    bf16x8 b = *(const bf16x8*)(ldsrow_ih + o);
                    if ((k0 >> 4) & 1) a1 = __builtin_amdgcn_mfma_f32_32x32x16_bf16(a, b, a1, 0, 0, 0);
                    else               a0 = __builtin_amdgcn_mfma_f32_32x32x16_bf16(a, b, a0, 0, 0, 0);
                }
                // wait: own cell data (RAW) + L1 readers of the buf we'll write (WAR)
                if (tid == 0) {
                    if (k >= 1) wait_ge(ready + d*64, 32u*(unsigned)k);
                    if (k >= 3) {
                        wait_ge(ready + 2*64, 32u*(unsigned)(k-2));
                        wait_ge(ready + 3*64, 32u*(unsigned)(k-2));
                    }
                }
                __syncthreads();
                // hidden segment (K=512) from buf rbuf cell d
                const ull* hp = hb + rb + (size_t)d*CELL64 + hoff;
                hcell_lds(hp, ldsrow_hh, rot, 1024, a0, a1);
                act_store(a0, a1, unitg, wm, l, creg, hreg,
                          hw + (size_t)wbuf*4*CELL64 + (size_t)d*CELL64);
                asm volatile("s_waitcnt vmcnt(0)" ::: "memory");
                __syncthreads();                       // all lanes' stores acked
                if (tid == 0)
                    __hip_atomic_fetch_add(ready + mycell*64, 1u,
                                           __ATOMIC_RELAXED, __HIP_MEMORY_SCOPE_AGENT);
            }
        } else {
            if (k >= 1) {
                f32x16 a0, a1;
#pragma unroll
                for (int r = 0; r < 16; ++r) { a0[r] = bias; a1[r] = 0.f; }
                // phase A: own hidden cell (self-group; usually already ready)
                if (tid == 0 && k >= 2) wait_ge(ready + (2+d)*64, 32u*(unsigned)(k-1));
                __syncthreads();
                const ull* hp2 = hb + rb + (size_t)(2+d)*CELL64 + hoff;
                hcell_glb(hp2, whh1_lane, a0, a1);
                // phase B: inputs from L0's cells 0,1 (buf rbuf, iter k-1 data)
                if (tid == 0) {
                    wait_ge(ready + 0*64, 32u*(unsigned)k);
                    wait_ge(ready + 1*64, 32u*(unsigned)k);
                }
                __syncthreads();
                const ull* hp0 = hb + rb + (size_t)0*CELL64 + hoff;
                hcell_lds(hp0, ldsrow_ih, rot,        2048, a0, a1);
                const ull* hp1 = hb + rb + (size_t)1*CELL64 + hoff;
                hcell_lds(hp1, ldsrow_ih, rot + 1024, 2048, a0, a1);
                act_store(a0, a1, unitg, wm, l, creg, hreg,
                          hw + (size_t)wbuf*4*CELL64 + (size_t)(2+d)*CELL64);
                asm volatile("s_waitcnt vmcnt(0)" ::: "memory");
                __syncthreads();
                if (tid == 0)
                    __hip_atomic_fetch_add(ready + mycell*64, 1u,
                                           __ATOMIC_RELAXED, __HIP_MEMORY_SCOPE_AGENT);
            }
        }
    }

    // final c + h write-out in PLAIN layout (h kept in registers)
    {
        float*          cc = cbuf   + (size_t)mycell * HS;
        unsigned short* hh = hplain + (size_t)mycell * HS;
        const int g = l & 3, hi = l >> 5;
#pragma unroll
        for (int q = 0; q < 4; ++q) {
            int row = 32*wm + g + 8*q + 4*hi;
            cc[(size_t)row * 512 + unitg] = creg[q];
            hh[(size_t)row * 512 + unitg] = f2bf(hreg[q]);
        }
    }
}

// ---------------------------------------------------------------------------
// Head (fp32 VALU; z from plain-layout final h/c)
// ---------------------------------------------------------------------------
__global__ __launch_bounds__(256) void head_kernel(
    const unsigned short* __restrict__ hplain,
    const float* __restrict__ cbuf,
    const float* __restrict__ eps,
    const float* __restrict__ Wmu,  const float* __restrict__ bmu,
    const float* __restrict__ Wvar, const float* __restrict__ bvar,
    float* __restrict__ out)
{
    const int tid = threadIdx.x;
    const int b   = tid & 63;
    const int i   = blockIdx.x * 4 + (tid >> 6);

    __shared__ float zs[KT][B + 1];

    float amu = 0.f, alv = 0.f;
    const float* wm = Wmu  + (size_t)i * ZDIM;
    const float* wv = Wvar + (size_t)i * ZDIM;

    for (int k0 = 0; k0 < ZDIM; k0 += KT) {
        __syncthreads();
        for (int idx = tid; idx < (B * KT) / 4; idx += 256) {
            int bb  = idx / (KT / 4);
            int kq4 = (idx % (KT / 4)) * 4;
            int zk  = k0 + kq4;
            int cell = zk >> 10;
            int m    = zk & 1023;
            float4 v;
            if (m < H) {
                const unsigned short* hs = hplain + (size_t)cell * HS + (size_t)bb * H + m;
                v.x = bf2f(hs[0]); v.y = bf2f(hs[1]); v.z = bf2f(hs[2]); v.w = bf2f(hs[3]);
            } else {
                v = *(const float4*)(cbuf + (size_t)cell * HS + (size_t)bb * H + (m - H));
            }
            zs[kq4 + 0][bb] = v.x; zs[kq4 + 1][bb] = v.y;
            zs[kq4 + 2][bb] = v.z; zs[kq4 + 3][bb] = v.w;
        }
        __syncthreads();
        #pragma unroll
        for (int kk = 0; kk < KT; kk += 4) {
            float4 a = *(const float4*)(wm + k0 + kk);
            float4 c = *(const float4*)(wv + k0 + kk);
            float z0 = zs[kk + 0][b], z1 = zs[kk + 1][b];
            float z2 = zs[kk + 2][b], z3 = zs[kk + 3][b];
            amu += a.x * z0 + a.y * z1 + a.z * z2 + a.w * z3;
            alv += c.x * z0 + c.y * z1 + c.z * z2 + c.w * z3;
        }
    }
    float mu = amu + bmu[i];
    float lv = alv + bvar[i];
    out[(size_t)b * ZDIM + i] = mu + eps[(size_t)b * ZDIM + i] * __expf(0.5f * lv);
}

// ---------------------------------------------------------------------------
extern "C" void kernel_launch(void* const* d_in, const int* in_sizes, int n_in,
                              void* d_out, int out_size, void* d_ws, size_t ws_size,
                              hipStream_t stream) {
    const float* input = (const float*)d_in[0];
    const float* eps   = (const float*)d_in[1];
    const float* w_ih0 = (const float*)d_in[2];
    const float* w_hh0 = (const float*)d_in[3];
    const float* b_ih0 = (const float*)d_in[4];
    const float* b_hh0 = (const float*)d_in[5];
    const float* w_ih1 = (const float*)d_in[6];
    const float* w_hh1 = (const float*)d_in[7];
    const float* b_ih1 = (const float*)d_in[8];
    const float* b_hh1 = (const float*)d_in[9];
    const float* W_mu  = (const float*)d_in[10];
    const float* b_mu  = (const float*)d_in[11];
    const float* W_var = (const float*)d_in[12];
    const float* b_var = (const float*)d_in[13];
    float* out = (float*)d_out;

    uint8_t* base = (uint8_t*)d_ws;
    size_t off = 0;
    auto alloc = [&](size_t bytes) -> void* {
        void* p = base + off;
        off += (bytes + 255) & ~(size_t)255;
        return p;
    };
    unsigned short* xb   = (unsigned short*)alloc((size_t)TSTEPS * B * E * 2);
    unsigned short* w0p  = (unsigned short*)alloc((size_t)2 * 2048 * E * 2);
    unsigned short* wh0p = (unsigned short*)alloc((size_t)2 * 2048 * H * 2);
    unsigned short* w1p  = (unsigned short*)alloc((size_t)2 * 2048 * 1024 * 2);
    unsigned short* wh1p = (unsigned short*)alloc((size_t)2 * 2048 * H * 2);
    float* b0p = (float*)alloc(2 * 2048 * 4);
    float* b1p = (float*)alloc(2 * 2048 * 4);
    unsigned* ready      = (unsigned*)alloc(1024);                    // 4 x 256B
    unsigned short* hbuf = (unsigned short*)alloc((size_t)3 * 4 * HS * 2);
    float* cbuf          = (float*)alloc((size_t)4 * HS * 4);
    unsigned short* hplain = (unsigned short*)alloc((size_t)4 * HS * 2);

    // zero ready + h (3 bufs) — contiguous region (cbuf/hplain fully written)
    hipMemsetAsync(ready, 0, 1024 + (size_t)3 * 4 * HS * 2, stream);

    conv_x_kernel<<<(TSTEPS * B * E / 8 + 255) / 256, 256, 0, stream>>>(input, xb, TSTEPS * B * E / 8);
    repack_w_kernel<<<(2 * 2048 * (E / 8) + 255) / 256, 256, 0, stream>>>(w_ih0, w0p, E);
    repack_w_kernel<<<(2 * 2048 * (H / 8) + 255) / 256, 256, 0, stream>>>(w_hh0, wh0p, H);
    repack_w_kernel<<<(2 * 2048 * (1024 / 8) + 255) / 256, 256, 0, stream>>>(w_ih1, w1p, 1024);
    repack_w_kernel<<<(2 * 2048 * (H / 8) + 255) / 256, 256, 0, stream>>>(w_hh1, wh1p, H);
    pack_bias_kernel<<<16, 256, 0, stream>>>(b_ih0, b_hh0, b0p);
    pack_bias_kernel<<<16, 256, 0, stream>>>(b_ih1, b_hh1, b1p);

    const size_t lds_bytes = 144 * 1024;
    hipFuncSetAttribute((const void*)persist_kernel,
                        hipFuncAttributeMaxDynamicSharedMemorySize, (int)lds_bytes);
    persist_kernel<<<PBLK, 256, lds_bytes, stream>>>(
        xb, w0p, wh0p, w1p, wh1p, b0p, b1p, hbuf, cbuf, hplain, ready);

    head_kernel<<<ZDIM / 4, 256, 0, stream>>>(hplain, cbuf, eps, W_mu, b_mu, W_var, b_var, out);
}

// Round 7
// 3607.747 us; speedup vs baseline: 2.2752x; 1.1379x over previous
//
#include <hip/hip_runtime.h>
#include <hip/hip_bf16.h>
#include <cstddef>
#include <cstdint>

#define B     64
#define S     256
#define E     640
#define H     512
#define TSTEPS (S - 1)       // 255
#define ZDIM  4096
#define KT    64
#define HS    (B * H)        // elems per state cell (32768)
#define PBLK  128            // persistent blocks
#define CELL64 8192          // u64 units per h cell (64*512*2B / 8)

typedef __attribute__((ext_vector_type(8)))  __bf16 bf16x8;
typedef __attribute__((ext_vector_type(16))) float  f32x16;
typedef unsigned long long ull;

__device__ __forceinline__ float sigf(float x) { return 1.0f / (1.0f + __expf(-x)); }
__device__ __forceinline__ float tanhfast(float x) { return 1.0f - 2.0f / (__expf(2.0f * x) + 1.0f); }

__device__ __forceinline__ unsigned short f2bf(float f) {
    union { float f; unsigned u; } x; x.f = f;
    unsigned r = x.u + 0x7fffu + ((x.u >> 16) & 1u);   // RNE
    return (unsigned short)(r >> 16);
}
__device__ __forceinline__ float bf2f(unsigned short u) {
    union { unsigned u; float f; } x; x.u = ((unsigned)u) << 16;
    return x.f;
}

__device__ __forceinline__ bf16x8 mk8(ull lo, ull hi) {
    union { ulonglong2 u; bf16x8 v; } x;
    x.u.x = lo; x.u.y = hi;
    return x.v;
}

#define HLOAD64(p)     __hip_atomic_load((p), __ATOMIC_RELAXED, __HIP_MEMORY_SCOPE_AGENT)
#define HSTORE64(p, v) __hip_atomic_store((p), (v), __ATOMIC_RELAXED, __HIP_MEMORY_SCOPE_AGENT)

// h-cell fragment layout (u64 granules):
//   idx = wm*4096 + m*128 + khalf*64 + plane*32 + row
//   granule = h[32*wm+row][k = m*16 + khalf*8 + plane*4 + 0..3]
// Consumer lane l, mfma m: lo = idx(m, l>>5, 0, l&31), hi = lo+32 => coalesced.

// ---------------------------------------------------------------------------
// Prep kernels
// ---------------------------------------------------------------------------
__global__ __launch_bounds__(256) void conv_x_kernel(
    const float* __restrict__ in, unsigned short* __restrict__ out, int n8)
{
    int i = blockIdx.x * 256 + threadIdx.x;
    if (i >= n8) return;
    const float4* p = (const float4*)(in + (size_t)i * 8);
    float4 a = p[0], b = p[1];
    unsigned short* o = out + (size_t)i * 8;
    o[0] = f2bf(a.x); o[1] = f2bf(a.y); o[2] = f2bf(a.z); o[3] = f2bf(a.w);
    o[4] = f2bf(b.x); o[5] = f2bf(b.y); o[6] = f2bf(b.z); o[7] = f2bf(b.w);
}

// out[d][n][k] = in[d][(n&3)*512 + (n>>2)][k], bf16  (gate-minor packing)
__global__ __launch_bounds__(256) void repack_w_kernel(
    const float* __restrict__ in, unsigned short* __restrict__ out, int K)
{
    int kc = K / 8;
    int i = blockIdx.x * 256 + threadIdx.x;
    if (i >= 2 * 2048 * kc) return;
    int k8 = i % kc;
    int n  = (i / kc) & 2047;
    int d  = i / (kc * 2048);
    int srow = (n & 3) * 512 + (n >> 2);
    const float* src = in + ((size_t)d * 2048 + srow) * K + (size_t)k8 * 8;
    unsigned short* dst = out + ((size_t)d * 2048 + n) * K + (size_t)k8 * 8;
    #pragma unroll
    for (int q = 0; q < 8; ++q) dst[q] = f2bf(src[q]);
}

__global__ __launch_bounds__(256) void pack_bias_kernel(
    const float* __restrict__ bih, const float* __restrict__ bhh, float* __restrict__ out)
{
    int i = blockIdx.x * 256 + threadIdx.x;   // 4096
    if (i >= 4096) return;
    int d = i >> 11, n = i & 2047;
    int s = d * 2048 + (n & 3) * 512 + (n >> 2);
    out[i] = bih[s] + bhh[s];
}

// ---------------------------------------------------------------------------
// Zero-RMW sync: flags[4][32], one 64B line per producer block.
//   slot value = 1 + index of last completed iter (L0: k+1; L1: k).
// All waves poll independently (no consumer-side barrier):
//   lanes 0..31 poll cell ca, lanes 32..63 poll cell cb.
// ---------------------------------------------------------------------------
__device__ __forceinline__ void poll2(const unsigned* flags, int ca, int cb,
                                      unsigned tgt, int l)
{
    const unsigned* p = flags + (size_t)((((l < 32) ? ca : cb) << 5) | (l & 31)) * 16;
    for (;;) {
        unsigned v = __hip_atomic_load(p, __ATOMIC_RELAXED, __HIP_MEMORY_SCOPE_AGENT);
        if (__all((int)(v >= tgt))) break;
        __builtin_amdgcn_s_sleep(1);
    }
}

// ---------------------------------------------------------------------------
// Coalesced coherent A-loads (fragment-order h) + MFMA consumers
// hp is pre-offset: cell_u64 + wm*4096 + (l>>5)*64 + (l&31)
// ---------------------------------------------------------------------------
__device__ __forceinline__ void issueM(ull* bf, const ull* hp, int mb) {
#pragma unroll
    for (int j = 0; j < 8; ++j) {
        bf[2*j]   = HLOAD64(hp + (size_t)(mb + j) * 128);
        bf[2*j+1] = HLOAD64(hp + (size_t)(mb + j) * 128 + 32);
    }
}

__device__ __forceinline__ void consume8_lds(const ull* bf, int mb,
    const char* ldsrow, int rotofs, int wrapB, f32x16& a0, f32x16& a1)
{
#pragma unroll
    for (int j = 0; j < 8; ++j) {
        bf16x8 a = mk8(bf[2*j], bf[2*j+1]);
        int o = (mb + j) * 32 + rotofs;
        o -= (o >= wrapB) ? wrapB : 0;
        bf16x8 b = *(const bf16x8*)(ldsrow + o);
        if ((mb + j) & 1) a1 = __builtin_amdgcn_mfma_f32_32x32x16_bf16(a, b, a1, 0, 0, 0);
        else              a0 = __builtin_amdgcn_mfma_f32_32x32x16_bf16(a, b, a0, 0, 0, 0);
    }
}

__device__ __forceinline__ void consume8_glb(const ull* bf, int mb,
    const unsigned short* wp, f32x16& a0, f32x16& a1)
{
#pragma unroll
    for (int j = 0; j < 8; ++j) {
        bf16x8 a = mk8(bf[2*j], bf[2*j+1]);
        bf16x8 b = *(const bf16x8*)(wp + (size_t)(mb + j) * 16);
        if ((mb + j) & 1) a1 = __builtin_amdgcn_mfma_f32_32x32x16_bf16(a, b, a1, 0, 0, 0);
        else              a0 = __builtin_amdgcn_mfma_f32_32x32x16_bf16(a, b, a0, 0, 0, 0);
    }
}

// full K=512 h-cell segment, B from LDS (3-deep rotating load batches)
__device__ __forceinline__ void hcell_lds(const ull* hp, const char* ldsrow,
    int rotofs, int wrapB, f32x16& a0, f32x16& a1)
{
    ull b0[16], b1[16], b2[16];
    issueM(b0, hp, 0); issueM(b1, hp, 8); issueM(b2, hp, 16);
    consume8_lds(b0, 0,  ldsrow, rotofs, wrapB, a0, a1);
    issueM(b0, hp, 24);
    consume8_lds(b1, 8,  ldsrow, rotofs, wrapB, a0, a1);
    consume8_lds(b2, 16, ldsrow, rotofs, wrapB, a0, a1);
    consume8_lds(b0, 24, ldsrow, rotofs, wrapB, a0, a1);
}

// full K=512 h-cell segment, B streamed from global (L2-hot weights)
__device__ __forceinline__ void hcell_glb(const ull* hp, const unsigned short* wp,
    f32x16& a0, f32x16& a1)
{
    ull b0[16], b1[16], b2[16];
    issueM(b0, hp, 0); issueM(b1, hp, 8); issueM(b2, hp, 16);
    consume8_glb(b0, 0,  wp, a0, a1);
    issueM(b0, hp, 24);
    consume8_glb(b1, 8,  wp, a0, a1);
    consume8_glb(b2, 16, wp, a0, a1);
    consume8_glb(b0, 24, wp, a0, a1);
}

// ---------------------------------------------------------------------------
// Activation + c/h-in-registers + coalesced fragment-order h store
// ---------------------------------------------------------------------------
__device__ __forceinline__ void act_store(
    const f32x16& a0, const f32x16& a1, int unitg, int wm, int l,
    float* creg, float* hreg, ull* hq_cell)
{
    const int g  = l & 3;
    const int hi = l >> 5;
    float gi[4], gf[4], gg[4], go[4];
#pragma unroll
    for (int r = 0; r < 16; ++r) {
        float v0 = a0[r] + a1[r];
        float v1 = __shfl_xor(v0, 1);
        float v2 = __shfl_xor(v0, 2);
        float v3 = __shfl_xor(v0, 3);
        float pv[4] = {v0, v1, v2, v3};
        const int rg = r & 3, q = r >> 2;
        if (g == rg) { gi[q] = pv[rg^0]; gf[q] = pv[rg^1]; gg[q] = pv[rg^2]; go[q] = pv[rg^3]; }
    }
    const int ubase = unitg & ~3;
    ull* dst = hq_cell + wm*4096 + (ubase >> 4)*128 + ((ubase >> 3) & 1)*64
                       + ((ubase >> 2) & 1)*32;
#pragma unroll
    for (int q = 0; q < 4; ++q) {
        int rl = g + 8*q + 4*hi;               // row within 32-row half
        float cold = creg[q];
        float cnew = sigf(gf[q]) * cold + sigf(gi[q]) * tanhfast(gg[q]);
        float hnew = sigf(go[q]) * tanhfast(cnew);
        creg[q] = cnew;
        hreg[q] = hnew;
        unsigned m  = f2bf(hnew);
        unsigned o1 = __shfl_xor(m, 4);
        unsigned d0 = (unitg & 1) ? ((m << 16) | o1) : ((o1 << 16) | m);
        unsigned o2 = __shfl_xor(d0, 8);
        ull q64 = (unitg & 2) ? (((ull)d0 << 32) | (ull)o2) : (((ull)o2 << 32) | (ull)d0);
        if ((l & 12) == 0)
            HSTORE64(dst + rl, q64);
    }
}

// ---------------------------------------------------------------------------
// Persistent recurrence kernel. 128 blocks x 256 threads, 144KB dynamic LDS.
// bid<64: L0; else L1. Block tile: 64 batch rows x 64 packed cols.
// Sync: per-producer flag slots (zero RMW); 3-buffer h rotation (WAR proof r5).
// ---------------------------------------------------------------------------
__global__ __launch_bounds__(256, 1) void persist_kernel(
    const unsigned short* __restrict__ xb,
    const unsigned short* __restrict__ w0p,
    const unsigned short* __restrict__ wh0p,
    const unsigned short* __restrict__ w1p,
    const unsigned short* __restrict__ wh1p,
    const float* __restrict__ b0p,
    const float* __restrict__ b1p,
    unsigned short* __restrict__ hbuf,   // (3 bufs,4 cells) fragment-order bf16
    float* __restrict__ cbuf,            // (4,64,512) f32 plain (final only)
    unsigned short* __restrict__ hplain, // (4,64,512) bf16 plain (final only)
    unsigned* __restrict__ flags)        // 4 cells x 32 slots x 64B
{
    extern __shared__ __align__(16) char lds[];
    const int tid = threadIdx.x;
    const int l   = tid & 63;
    const int w   = tid >> 6;
    const int wm  = w & 1, wn = w >> 1;
    const int bid = blockIdx.x;
    const bool isL1 = bid >= 64;
    const int g2 = bid & 63;
    const int d  = g2 >> 5;
    const int n0 = (g2 & 31) * 64;
    const int myslot = g2 & 31;
    const int lrow  = wn * 32 + (l & 31);    // weight row (output col), local
    const int khalf = l >> 5;
    const int HHOFF = 64 * 1280;             // L0 hh region offset

    // ---- stage weights into LDS (16B-per-row rotate, exact strides) --------
    if (!isL1) {
        for (int idx = tid; idx < 64 * 80; idx += 256) {   // ih: 64 x 640
            int r = idx / 80, k8 = idx % 80;
            bf16x8 v = *(const bf16x8*)(w0p + ((size_t)d*2048 + n0 + r)*640 + (size_t)k8*8);
            int o = k8*16 + r*16; o -= (o >= 1280) ? 1280 : 0;
            *(bf16x8*)(lds + r*1280 + o) = v;
        }
        for (int idx = tid; idx < 64 * 64; idx += 256) {   // hh: 64 x 512
            int r = idx / 64, k8 = idx % 64;
            bf16x8 v = *(const bf16x8*)(wh0p + ((size_t)d*2048 + n0 + r)*512 + (size_t)k8*8);
            int o = k8*16 + r*16; o -= (o >= 1024) ? 1024 : 0;
            *(bf16x8*)(lds + HHOFF + r*1024 + o) = v;
        }
    } else {
        for (int idx = tid; idx < 64 * 128; idx += 256) {  // ih: 64 x 1024
            int r = idx / 128, k8 = idx % 128;
            bf16x8 v = *(const bf16x8*)(w1p + ((size_t)d*2048 + n0 + r)*1024 + (size_t)k8*8);
            int o = k8*16 + r*16; o -= (o >= 2048) ? 2048 : 0;
            *(bf16x8*)(lds + r*2048 + o) = v;
        }
    }
    __syncthreads();

    const int IHB = isL1 ? 2048 : 1280;
    const float bias = (isL1 ? b1p : b0p)[d*2048 + n0 + lrow];
    const char* ldsrow_ih = lds + (size_t)lrow * IHB;
    const char* ldsrow_hh = lds + HHOFF + (size_t)lrow * 1024;
    const int rot = lrow * 16 + khalf * 16;
    const int unitg = ((n0 + lrow) >> 2);
    const int hoff  = wm*4096 + khalf*64 + (l & 31);   // consumer A-frag offset
    const int arow  = wm * 32 + (l & 31);              // batch row (x segment)
    float creg[4] = {0.f, 0.f, 0.f, 0.f};
    float hreg[4] = {0.f, 0.f, 0.f, 0.f};
    const ull* hb = (const ull*)hbuf;
    ull*       hw = (ull*)hbuf;
    const unsigned short* whh1_lane =
        wh1p + ((size_t)d*2048 + n0 + lrow) * 512 + khalf * 8;
    const int mycell = isL1 ? (2 + d) : d;
    unsigned* myflag = flags + (size_t)((mycell << 5) | myslot) * 16;

    for (int k = 0; k <= TSTEPS; ++k) {
        const int rbuf = k % 3, wbuf = (k + 1) % 3;
        const size_t rb = (size_t)rbuf * 4 * CELL64;
        if (!isL1) {
            if (k < TSTEPS) {
                f32x16 a0, a1;
#pragma unroll
                for (int r = 0; r < 16; ++r) { a0[r] = bias; a1[r] = 0.f; }
                // x segment (K=640) — independent of recurrence, off critical path
                const unsigned short* Ax = xb + (size_t)k*B*E + (size_t)arow*E + khalf*8;
#pragma unroll 8
                for (int k0 = 0; k0 < E; k0 += 16) {
                    bf16x8 a = *(const bf16x8*)(Ax + k0);
                    int o = k0*2 + rot; o -= (o >= 1280) ? 1280 : 0;
                    bf16x8 b = *(const bf16x8*)(ldsrow_ih + o);
                    if ((k0 >> 4) & 1) a1 = __builtin_amdgcn_mfma_f32_32x32x16_bf16(a, b, a1, 0, 0, 0);
                    else               a0 = __builtin_amdgcn_mfma_f32_32x32x16_bf16(a, b, a0, 0, 0, 0);
                }
                // RAW: own cell iter k-1 data visible (L0 slots hold k after iter k-1)
                if (k >= 1) poll2(flags, d, d, (unsigned)k, l);
                const ull* hp = hb + rb + (size_t)d*CELL64 + hoff;
                hcell_lds(hp, ldsrow_hh, rot, 1024, a0, a1);
                // WAR: L1 readers of buf wbuf done (L1 slots hold j after iter j)
                if (k >= 3) poll2(flags, 2, 3, (unsigned)(k - 2), l);
                act_store(a0, a1, unitg, wm, l, creg, hreg,
                          hw + (size_t)wbuf*4*CELL64 + (size_t)d*CELL64);
                asm volatile("s_waitcnt vmcnt(0)" ::: "memory");
                __syncthreads();                       // all waves' stores acked
                if (tid == 0)
                    __hip_atomic_store(myflag, (unsigned)(k + 1),
                                       __ATOMIC_RELAXED, __HIP_MEMORY_SCOPE_AGENT);
            }
        } else {
            if (k >= 1) {
                f32x16 a0, a1;
#pragma unroll
                for (int r = 0; r < 16; ++r) { a0[r] = bias; a1[r] = 0.f; }
                // phase A: own hidden cell (self-group; usually already ready)
                if (k >= 2) poll2(flags, 2 + d, 2 + d, (unsigned)(k - 1), l);
                const ull* hp2 = hb + rb + (size_t)(2+d)*CELL64 + hoff;
                hcell_glb(hp2, whh1_lane, a0, a1);
                // phase B: inputs from L0's cells 0,1 (iter k-1 data: slots >= k)
                poll2(flags, 0, 1, (unsigned)k, l);
                const ull* hp0 = hb + rb + (size_t)0*CELL64 + hoff;
                hcell_lds(hp0, ldsrow_ih, rot,        2048, a0, a1);
                const ull* hp1 = hb + rb + (size_t)1*CELL64 + hoff;
                hcell_lds(hp1, ldsrow_ih, rot + 1024, 2048, a0, a1);
                act_store(a0, a1, unitg, wm, l, creg, hreg,
                          hw + (size_t)wbuf*4*CELL64 + (size_t)(2+d)*CELL64);
                asm volatile("s_waitcnt vmcnt(0)" ::: "memory");
                __syncthreads();
                if (tid == 0)
                    __hip_atomic_store(myflag, (unsigned)k,
                                       __ATOMIC_RELAXED, __HIP_MEMORY_SCOPE_AGENT);
            }
        }
    }

    // final c + h write-out in PLAIN layout (h kept in registers)
    {
        float*          cc = cbuf   + (size_t)mycell * HS;
        unsigned short* hh = hplain + (size_t)mycell * HS;
        const int g = l & 3, hi = l >> 5;
#pragma unroll
        for (int q = 0; q < 4; ++q) {
            int row = 32*wm + g + 8*q + 4*hi;
            cc[(size_t)row * 512 + unitg] = creg[q];
            hh[(size_t)row * 512 + unitg] = f2bf(hreg[q]);
        }
    }
}

// ---------------------------------------------------------------------------
// Head (fp32 VALU; z from plain-layout final h/c)
// ---------------------------------------------------------------------------
__global__ __launch_bounds__(256) void head_kernel(
    const unsigned short* __restrict__ hplain,
    const float* __restrict__ cbuf,
    const float* __restrict__ eps,
    const float* __restrict__ Wmu,  const float* __restrict__ bmu,
    const float* __restrict__ Wvar, const float* __restrict__ bvar,
    float* __restrict__ out)
{
    const int tid = threadIdx.x;
    const int b   = tid & 63;
    const int i   = blockIdx.x * 4 + (tid >> 6);

    __shared__ float zs[KT][B + 1];

    float amu = 0.f, alv = 0.f;
    const float* wm = Wmu  + (size_t)i * ZDIM;
    const float* wv = Wvar + (size_t)i * ZDIM;

    for (int k0 = 0; k0 < ZDIM; k0 += KT) {
        __syncthreads();
        for (int idx = tid; idx < (B * KT) / 4; idx += 256) {
            int bb  = idx / (KT / 4);
            int kq4 = (idx % (KT / 4)) * 4;
            int zk  = k0 + kq4;
            int cell = zk >> 10;
            int m    = zk & 1023;
            float4 v;
            if (m < H) {
                const unsigned short* hs = hplain + (size_t)cell * HS + (size_t)bb * H + m;
                v.x = bf2f(hs[0]); v.y = bf2f(hs[1]); v.z = bf2f(hs[2]); v.w = bf2f(hs[3]);
            } else {
                v = *(const float4*)(cbuf + (size_t)cell * HS + (size_t)bb * H + (m - H));
            }
            zs[kq4 + 0][bb] = v.x; zs[kq4 + 1][bb] = v.y;
            zs[kq4 + 2][bb] = v.z; zs[kq4 + 3][bb] = v.w;
        }
        __syncthreads();
        #pragma unroll
        for (int kk = 0; kk < KT; kk += 4) {
            float4 a = *(const float4*)(wm + k0 + kk);
            float4 c = *(const float4*)(wv + k0 + kk);
            float z0 = zs[kk + 0][b], z1 = zs[kk + 1][b];
            float z2 = zs[kk + 2][b], z3 = zs[kk + 3][b];
            amu += a.x * z0 + a.y * z1 + a.z * z2 + a.w * z3;
            alv += c.x * z0 + c.y * z1 + c.z * z2 + c.w * z3;
        }
    }
    float mu = amu + bmu[i];
    float lv = alv + bvar[i];
    out[(size_t)b * ZDIM + i] = mu + eps[(size_t)b * ZDIM + i] * __expf(0.5f * lv);
}

// ---------------------------------------------------------------------------
extern "C" void kernel_launch(void* const* d_in, const int* in_sizes, int n_in,
                              void* d_out, int out_size, void* d_ws, size_t ws_size,
                              hipStream_t stream) {
    const float* input = (const float*)d_in[0];
    const float* eps   = (const float*)d_in[1];
    const float* w_ih0 = (const float*)d_in[2];
    const float* w_hh0 = (const float*)d_in[3];
    const float* b_ih0 = (const float*)d_in[4];
    const float* b_hh0 = (const float*)d_in[5];
    const float* w_ih1 = (const float*)d_in[6];
    const float* w_hh1 = (const float*)d_in[7];
    const float* b_ih1 = (const float*)d_in[8];
    const float* b_hh1 = (const float*)d_in[9];
    const float* W_mu  = (const float*)d_in[10];
    const float* b_mu  = (const float*)d_in[11];
    const float* W_var = (const float*)d_in[12];
    const float* b_var = (const float*)d_in[13];
    float* out = (float*)d_out;

    uint8_t* base = (uint8_t*)d_ws;
    size_t off = 0;
    auto alloc = [&](size_t bytes) -> void* {
        void* p = base + off;
        off += (bytes + 255) & ~(size_t)255;
        return p;
    };
    unsigned short* xb   = (unsigned short*)alloc((size_t)TSTEPS * B * E * 2);
    unsigned short* w0p  = (unsigned short*)alloc((size_t)2 * 2048 * E * 2);
    unsigned short* wh0p = (unsigned short*)alloc((size_t)2 * 2048 * H * 2);
    unsigned short* w1p  = (unsigned short*)alloc((size_t)2 * 2048 * 1024 * 2);
    unsigned short* wh1p = (unsigned short*)alloc((size_t)2 * 2048 * H * 2);
    float* b0p = (float*)alloc(2 * 2048 * 4);
    float* b1p = (float*)alloc(2 * 2048 * 4);
    unsigned* flags      = (unsigned*)alloc(4 * 32 * 64);             // 8KB
    unsigned short* hbuf = (unsigned short*)alloc((size_t)3 * 4 * HS * 2);
    float* cbuf          = (float*)alloc((size_t)4 * HS * 4);
    unsigned short* hplain = (unsigned short*)alloc((size_t)4 * HS * 2);

    // zero flags + h (3 bufs) — contiguous region (cbuf/hplain fully written)
    hipMemsetAsync(flags, 0, 4 * 32 * 64 + (size_t)3 * 4 * HS * 2, stream);

    conv_x_kernel<<<(TSTEPS * B * E / 8 + 255) / 256, 256, 0, stream>>>(input, xb, TSTEPS * B * E / 8);
    repack_w_kernel<<<(2 * 2048 * (E / 8) + 255) / 256, 256, 0, stream>>>(w_ih0, w0p, E);
    repack_w_kernel<<<(2 * 2048 * (H / 8) + 255) / 256, 256, 0, stream>>>(w_hh0, wh0p, H);
    repack_w_kernel<<<(2 * 2048 * (1024 / 8) + 255) / 256, 256, 0, stream>>>(w_ih1, w1p, 1024);
    repack_w_kernel<<<(2 * 2048 * (H / 8) + 255) / 256, 256, 0, stream>>>(w_hh1, wh1p, H);
    pack_bias_kernel<<<16, 256, 0, stream>>>(b_ih0, b_hh0, b0p);
    pack_bias_kernel<<<16, 256, 0, stream>>>(b_ih1, b_hh1, b1p);

    const size_t lds_bytes = 144 * 1024;
    hipFuncSetAttribute((const void*)persist_kernel,
                        hipFuncAttributeMaxDynamicSharedMemorySize, (int)lds_bytes);
    persist_kernel<<<PBLK, 256, lds_bytes, stream>>>(
        xb, w0p, wh0p, w1p, wh1p, b0p, b1p, hbuf, cbuf, hplain, flags);

    head_kernel<<<ZDIM / 4, 256, 0, stream>>>(hplain, cbuf, eps, W_mu, b_mu, W_var, b_var, out);
}

// Round 8
// 3297.862 us; speedup vs baseline: 2.4890x; 1.0940x over previous
//
#include <hip/hip_runtime.h>
#include <hip/hip_bf16.h>
#include <cstddef>
#include <cstdint>

#define B     64
#define S     256
#define E     640
#define H     512
#define TSTEPS (S - 1)       // 255
#define ZDIM  4096
#define KT    64
#define HS    (B * H)        // elems per state cell (32768)
#define CELL64 8192          // u64 units per h cell (64*512*2B / 8)

typedef __attribute__((ext_vector_type(8)))  __bf16 bf16x8;
typedef __attribute__((ext_vector_type(16))) float  f32x16;
typedef unsigned long long ull;

__device__ __forceinline__ float sigf(float x) { return 1.0f / (1.0f + __expf(-x)); }
__device__ __forceinline__ float tanhfast(float x) { return 1.0f - 2.0f / (__expf(2.0f * x) + 1.0f); }

__device__ __forceinline__ unsigned short f2bf(float f) {
    union { float f; unsigned u; } x; x.f = f;
    unsigned r = x.u + 0x7fffu + ((x.u >> 16) & 1u);   // RNE
    return (unsigned short)(r >> 16);
}
__device__ __forceinline__ float bf2f(unsigned short u) {
    union { unsigned u; float f; } x; x.u = ((unsigned)u) << 16;
    return x.f;
}
__device__ __forceinline__ unsigned pk2(float a, float b) {
    return (unsigned)f2bf(a) | ((unsigned)f2bf(b) << 16);
}

#define HSTORE64(p, v) __hip_atomic_store((p), (v), __ATOMIC_RELAXED, __HIP_MEMORY_SCOPE_AGENT)
#define HSTORE32(p, v) __hip_atomic_store((p), (v), __ATOMIC_RELAXED, __HIP_MEMORY_SCOPE_AGENT)
#define HLOAD32(p)     __hip_atomic_load((p), __ATOMIC_RELAXED, __HIP_MEMORY_SCOPE_AGENT)

// Coherent (coherence-point) 16B load, pipelined plain VMEM, bypass L1/L2.
__device__ __forceinline__ uint4 cld16(const void* p) {
    uint4 v;
    asm volatile("global_load_dwordx4 %0, %1, off sc0 sc1"
                 : "=v"(v) : "v"(p) : "memory");
    return v;
}
__device__ __forceinline__ void cwait0() {
    asm volatile("s_waitcnt vmcnt(0)" ::: "memory");
    __builtin_amdgcn_sched_barrier(0);
}
__device__ __forceinline__ bf16x8 u2b(uint4 u) {
    union { uint4 u; bf16x8 b; } x; x.u = u; return x.b;
}

// h-cell fragment layout (u64 granules):
//   idx = wm*4096 + m*128 + khalf*64 + row*2 + plane
//   granule = h[32*wm+row][k = m*16 + khalf*8 + plane*4 + 0..3]
// Consumer lane l, mfma m: 16B at (wm*4096 + m*128 + (l>>5)*64 + (l&31)*2)
// => planes 0,1 contiguous per lane; 32 lanes x 16B consecutive.

// ---------------------------------------------------------------------------
// Prep kernels
// ---------------------------------------------------------------------------
__global__ __launch_bounds__(256) void conv_x_kernel(
    const float* __restrict__ in, unsigned short* __restrict__ out, int n8)
{
    int i = blockIdx.x * 256 + threadIdx.x;
    if (i >= n8) return;
    const float4* p = (const float4*)(in + (size_t)i * 8);
    float4 a = p[0], b = p[1];
    unsigned short* o = out + (size_t)i * 8;
    o[0] = f2bf(a.x); o[1] = f2bf(a.y); o[2] = f2bf(a.z); o[3] = f2bf(a.w);
    o[4] = f2bf(b.x); o[5] = f2bf(b.y); o[6] = f2bf(b.z); o[7] = f2bf(b.w);
}

// out[d][n][k] = in[d][(n&3)*512 + (n>>2)][k], bf16  (gate-minor packing)
__global__ __launch_bounds__(256) void repack_w_kernel(
    const float* __restrict__ in, unsigned short* __restrict__ out, int K)
{
    int kc = K / 8;
    int i = blockIdx.x * 256 + threadIdx.x;
    if (i >= 2 * 2048 * kc) return;
    int k8 = i % kc;
    int n  = (i / kc) & 2047;
    int d  = i / (kc * 2048);
    int srow = (n & 3) * 512 + (n >> 2);
    const float* src = in + ((size_t)d * 2048 + srow) * K + (size_t)k8 * 8;
    unsigned short* dst = out + ((size_t)d * 2048 + n) * K + (size_t)k8 * 8;
    #pragma unroll
    for (int q = 0; q < 8; ++q) dst[q] = f2bf(src[q]);
}

__global__ __launch_bounds__(256) void pack_bias_kernel(
    const float* __restrict__ bih, const float* __restrict__ bhh, float* __restrict__ out)
{
    int i = blockIdx.x * 256 + threadIdx.x;   // 4096
    if (i >= 4096) return;
    int d = i >> 11, n = i & 2047;
    int s = d * 2048 + (n & 3) * 512 + (n >> 2);
    out[i] = bih[s] + bhh[s];
}

// ---------------------------------------------------------------------------
// x-projection GEMM: xp[t][d] = x_t @ wih0^T  (bf16, MFMA C-fragment order)
// grid (64, 4): bx = d*32 + n0tile, by = t-chunk of 64. 256 thr, 80KB LDS.
// Tile layout: elem idx = ((((t*2+d)*64 + colblk)*2 + wm)*1024) + l*16 + r
// ---------------------------------------------------------------------------
__global__ __launch_bounds__(256) void xproj_kernel(
    const unsigned short* __restrict__ xb,
    const unsigned short* __restrict__ w0p,
    unsigned short* __restrict__ xp)
{
    extern __shared__ __align__(16) char lds[];
    const int tid = threadIdx.x;
    const int l   = tid & 63;
    const int w   = tid >> 6;
    const int wm  = w & 1, wn = w >> 1;
    const int d   = blockIdx.x >> 5;
    const int n0  = (blockIdx.x & 31) * 64;

    for (int idx = tid; idx < 64 * 80; idx += 256) {   // ih: 64 x 640
        int r = idx / 80, k8 = idx % 80;
        bf16x8 v = *(const bf16x8*)(w0p + ((size_t)d*2048 + n0 + r)*640 + (size_t)k8*8);
        int o = k8*16 + r*16; o -= (o >= 1280) ? 1280 : 0;
        *(bf16x8*)(lds + r*1280 + o) = v;
    }
    __syncthreads();

    const int lrow  = wn * 32 + (l & 31);
    const int khalf = l >> 5;
    const char* ldsrow = lds + (size_t)lrow * 1280;
    const int rot = lrow * 16 + khalf * 16;
    const int t0 = blockIdx.y * 64;
    const int t1 = (t0 + 64 < TSTEPS) ? (t0 + 64) : TSTEPS;

    for (int t = t0; t < t1; ++t) {
        f32x16 a0, a1;
#pragma unroll
        for (int r = 0; r < 16; ++r) { a0[r] = 0.f; a1[r] = 0.f; }
        const unsigned short* Ax = xb + ((size_t)t*B + wm*32 + (l & 31))*E + khalf*8;
#pragma unroll 8
        for (int k0 = 0; k0 < E; k0 += 16) {
            bf16x8 a = *(const bf16x8*)(Ax + k0);
            int o = k0*2 + rot; o -= (o >= 1280) ? 1280 : 0;
            bf16x8 b = *(const bf16x8*)(ldsrow + o);
            if ((k0 >> 4) & 1) a1 = __builtin_amdgcn_mfma_f32_32x32x16_bf16(a, b, a1, 0, 0, 0);
            else               a0 = __builtin_amdgcn_mfma_f32_32x32x16_bf16(a, b, a0, 0, 0, 0);
        }
        size_t base = ((((size_t)t*2 + d)*64 + (n0 >> 5) + wn)*2 + wm)*1024 + (size_t)l*16;
        unsigned short* dst = xp + base;
        uint4 o0, o1;
        o0.x = pk2(a0[0]+a1[0],  a0[1]+a1[1]);
        o0.y = pk2(a0[2]+a1[2],  a0[3]+a1[3]);
        o0.z = pk2(a0[4]+a1[4],  a0[5]+a1[5]);
        o0.w = pk2(a0[6]+a1[6],  a0[7]+a1[7]);
        o1.x = pk2(a0[8]+a1[8],  a0[9]+a1[9]);
        o1.y = pk2(a0[10]+a1[10], a0[11]+a1[11]);
        o1.z = pk2(a0[12]+a1[12], a0[13]+a1[13]);
        o1.w = pk2(a0[14]+a1[14], a0[15]+a1[15]);
        *(uint4*)dst       = o0;
        *(uint4*)(dst + 8) = o1;
    }
}

// ---------------------------------------------------------------------------
// Polls (per-wave flags: 4 cells x 128 slots x 64B)
// ---------------------------------------------------------------------------
__device__ __forceinline__ void poll1(const unsigned* flags, int cell,
                                      unsigned tgt, int l)
{
    const unsigned* p0 = flags + (size_t)(cell*128 + l) * 16;
    for (;;) {
        unsigned a = HLOAD32(p0);
        unsigned b = HLOAD32(p0 + 64*16);
        unsigned v = a < b ? a : b;
        if (__all((int)(v >= tgt))) break;
        __builtin_amdgcn_s_sleep(1);
    }
}
__device__ __forceinline__ void poll2c(const unsigned* flags, int ca, int cb,
                                       unsigned tgt, int l)
{
    const unsigned* p0 = flags + (size_t)(ca*128 + l) * 16;
    const unsigned* p1 = flags + (size_t)(cb*128 + l) * 16;
    for (;;) {
        unsigned a = HLOAD32(p0);
        unsigned b = HLOAD32(p0 + 64*16);
        unsigned c = HLOAD32(p1);
        unsigned e = HLOAD32(p1 + 64*16);
        unsigned v = a < b ? a : b;
        unsigned u = c < e ? c : e;
        v = v < u ? v : u;
        if (__all((int)(v >= tgt))) break;
        __builtin_amdgcn_s_sleep(1);
    }
}

// ---------------------------------------------------------------------------
// Coherent h-cell consumers (32 x 16B pipelined loads, one drain)
// hp byte base pre-offset: cell + wm*4096 + khalf*64 + (l&31)*2  (u64 units)
// ---------------------------------------------------------------------------
__device__ __forceinline__ void hcell_c_lds(const void* hp, const char* ldsrow,
    int rotofs, int wrapB, f32x16& a0, f32x16& a1)
{
    uint4 hv[32];
#pragma unroll
    for (int m = 0; m < 32; ++m)
        hv[m] = cld16((const char*)hp + (size_t)m * 1024);
    cwait0();
#pragma unroll
    for (int m = 0; m < 32; ++m) {
        int o = m*32 + rotofs; o -= (o >= wrapB) ? wrapB : 0;
        bf16x8 b = *(const bf16x8*)(ldsrow + o);
        bf16x8 a = u2b(hv[m]);
        if (m & 1) a1 = __builtin_amdgcn_mfma_f32_32x32x16_bf16(a, b, a1, 0, 0, 0);
        else       a0 = __builtin_amdgcn_mfma_f32_32x32x16_bf16(a, b, a0, 0, 0, 0);
    }
}

__device__ __forceinline__ void hcell_c_reg(const void* hp, const bf16x8* wh,
    f32x16& a0, f32x16& a1)
{
    uint4 hv[32];
#pragma unroll
    for (int m = 0; m < 32; ++m)
        hv[m] = cld16((const char*)hp + (size_t)m * 1024);
    cwait0();
#pragma unroll
    for (int m = 0; m < 32; ++m) {
        bf16x8 a = u2b(hv[m]);
        if (m & 1) a1 = __builtin_amdgcn_mfma_f32_32x32x16_bf16(a, wh[m], a1, 0, 0, 0);
        else       a0 = __builtin_amdgcn_mfma_f32_32x32x16_bf16(a, wh[m], a0, 0, 0, 0);
    }
}

// ---------------------------------------------------------------------------
// Activation + c/h-in-registers + coalesced fragment-order h store
// ---------------------------------------------------------------------------
template<bool XADD>
__device__ __forceinline__ void act_store(
    const f32x16& a0, const f32x16& a1, bf16x8 xpa, bf16x8 xpb,
    int unitg, int wm, int l, float* creg, float* hreg, ull* hq_cell)
{
    const int g  = l & 3;
    const int hi = l >> 5;
    union { bf16x8 v; unsigned short s[8]; } ua, ub;
    ua.v = xpa; ub.v = xpb;
    float gi[4], gf[4], gg[4], go[4];
#pragma unroll
    for (int r = 0; r < 16; ++r) {
        float v0 = a0[r] + a1[r];
        if (XADD) v0 += bf2f((r < 8) ? ua.s[r] : ub.s[r - 8]);
        float v1 = __shfl_xor(v0, 1);
        float v2 = __shfl_xor(v0, 2);
        float v3 = __shfl_xor(v0, 3);
        float pv[4] = {v0, v1, v2, v3};
        const int rg = r & 3, q = r >> 2;
        if (g == rg) { gi[q] = pv[rg^0]; gf[q] = pv[rg^1]; gg[q] = pv[rg^2]; go[q] = pv[rg^3]; }
    }
    const int ubase = unitg & ~3;
    ull* dst = hq_cell + wm*4096 + (ubase >> 4)*128 + ((ubase >> 3) & 1)*64
                       + ((ubase >> 2) & 1);
#pragma unroll
    for (int q = 0; q < 4; ++q) {
        int rl = g + 8*q + 4*hi;               // row within 32-row half
        float cold = creg[q];
        float cnew = sigf(gf[q]) * cold + sigf(gi[q]) * tanhfast(gg[q]);
        float hnew = sigf(go[q]) * tanhfast(cnew);
        creg[q] = cnew;
        hreg[q] = hnew;
        unsigned m  = f2bf(hnew);
        unsigned o1 = __shfl_xor(m, 4);
        unsigned d0 = (unitg & 1) ? ((m << 16) | o1) : ((o1 << 16) | m);
        unsigned o2 = __shfl_xor(d0, 8);
        ull q64 = (unitg & 2) ? (((ull)d0 << 32) | (ull)o2) : (((ull)o2 << 32) | (ull)d0);
        if ((l & 12) == 0)
            HSTORE64(dst + rl*2, q64);
    }
}

// ---------------------------------------------------------------------------
// Persistent recurrence. 128 blocks x 256 thr, 144KB dyn LDS.
// bid<64: L0; else L1. Sync: per-wave flag slots; 3-buffer h rotation.
// XPRE=1: L0 input projection precomputed (xp); L0 stages only whh in LDS.
// ---------------------------------------------------------------------------
template<int XPRE>
__global__ __launch_bounds__(256, 1) void persist_kernel(
    const unsigned short* __restrict__ xb,
    const unsigned short* __restrict__ w0p,
    const unsigned short* __restrict__ wh0p,
    const unsigned short* __restrict__ w1p,
    const unsigned short* __restrict__ wh1p,
    const float* __restrict__ b0p,
    const float* __restrict__ b1p,
    const unsigned short* __restrict__ xp,
    unsigned short* __restrict__ hbuf,   // (3 bufs,4 cells) fragment-order bf16
    float* __restrict__ cbuf,            // (4,64,512) f32 plain (final only)
    unsigned short* __restrict__ hplain, // (4,64,512) bf16 plain (final only)
    unsigned* __restrict__ flags)        // 4 cells x 128 slots x 64B
{
    extern __shared__ __align__(16) char lds[];
    const int tid = threadIdx.x;
    const int l   = tid & 63;
    const int w   = tid >> 6;
    const int wm  = w & 1, wn = w >> 1;
    const int bid = blockIdx.x;
    const bool isL1 = bid >= 64;
    const int g2 = bid & 63;
    const int d  = g2 >> 5;
    const int n0 = (g2 & 31) * 64;
    const int myslot = g2 & 31;
    const int lrow  = wn * 32 + (l & 31);
    const int khalf = l >> 5;
    const int HHOFF = 64 * 1280;             // L0 hh offset (XPRE=0 layout)

    // ---- stage weights into LDS --------------------------------------------
    if (!isL1) {
        if (!XPRE) {
            for (int idx = tid; idx < 64 * 80; idx += 256) {   // ih: 64 x 640
                int r = idx / 80, k8 = idx % 80;
                bf16x8 v = *(const bf16x8*)(w0p + ((size_t)d*2048 + n0 + r)*640 + (size_t)k8*8);
                int o = k8*16 + r*16; o -= (o >= 1280) ? 1280 : 0;
                *(bf16x8*)(lds + r*1280 + o) = v;
            }
        }
        const int hb0 = XPRE ? 0 : HHOFF;
        for (int idx = tid; idx < 64 * 64; idx += 256) {       // hh: 64 x 512
            int r = idx / 64, k8 = idx % 64;
            bf16x8 v = *(const bf16x8*)(wh0p + ((size_t)d*2048 + n0 + r)*512 + (size_t)k8*8);
            int o = k8*16 + r*16; o -= (o >= 1024) ? 1024 : 0;
            *(bf16x8*)(lds + hb0 + r*1024 + o) = v;
        }
    } else {
        for (int idx = tid; idx < 64 * 128; idx += 256) {      // ih: 64 x 1024
            int r = idx / 128, k8 = idx % 128;
            bf16x8 v = *(const bf16x8*)(w1p + ((size_t)d*2048 + n0 + r)*1024 + (size_t)k8*8);
            int o = k8*16 + r*16; o -= (o >= 2048) ? 2048 : 0;
            *(bf16x8*)(lds + r*2048 + o) = v;
        }
    }
    __syncthreads();

    const float bias = (isL1 ? b1p : b0p)[d*2048 + n0 + lrow];
    const char* ldsrow_ih = lds + (size_t)lrow * (isL1 ? 2048 : 1280);
    const char* ldsrow_hh = lds + (XPRE ? 0 : HHOFF) + (size_t)lrow * 1024;
    const int rot = lrow * 16 + khalf * 16;
    const int unitg = ((n0 + lrow) >> 2);
    const int hoff  = wm*4096 + khalf*64 + (l & 31)*2;   // consumer u64 offset
    const int arow  = wm * 32 + (l & 31);
    float creg[4] = {0.f, 0.f, 0.f, 0.f};
    float hreg[4] = {0.f, 0.f, 0.f, 0.f};
    const ull* hb = (const ull*)hbuf;
    ull*       hw = (ull*)hbuf;
    const int mycell = isL1 ? (2 + d) : d;
    unsigned* myflag = flags + (size_t)(mycell*128 + myslot*4 + w) * 16;
    bf16x8 zero8 = {};

    // L1: preload whh B-fragments into registers (phase A is pure reg-MFMA)
    bf16x8 wh[32];
    if (isL1) {
        const unsigned short* whl = wh1p + ((size_t)d*2048 + n0 + lrow)*512 + khalf*8;
#pragma unroll
        for (int m = 0; m < 32; ++m) wh[m] = *(const bf16x8*)(whl + m*16);
    }

    for (int k = 0; k <= TSTEPS; ++k) {
        const int rbuf = k % 3, wbuf = (k + 1) % 3;
        const size_t rb = (size_t)rbuf * 4 * CELL64;
        if (!isL1) {
            if (k < TSTEPS) {
                f32x16 a0, a1;
#pragma unroll
                for (int r = 0; r < 16; ++r) { a0[r] = bias; a1[r] = 0.f; }
                bf16x8 xpa = zero8, xpb = zero8;
                if (XPRE) {
                    // prefetch this step's x-projection (hidden under poll)
                    size_t base = ((((size_t)k*2 + d)*64 + (n0 >> 5) + wn)*2 + wm)*1024
                                  + (size_t)l*16;
                    xpa = *(const bf16x8*)(xp + base);
                    xpb = *(const bf16x8*)(xp + base + 8);
                } else {
                    const unsigned short* Ax = xb + (size_t)k*B*E + (size_t)arow*E + khalf*8;
#pragma unroll 8
                    for (int k0 = 0; k0 < E; k0 += 16) {
                        bf16x8 a = *(const bf16x8*)(Ax + k0);
                        int o = k0*2 + rot; o -= (o >= 1280) ? 1280 : 0;
                        bf16x8 b = *(const bf16x8*)(ldsrow_ih + o);
                        if ((k0 >> 4) & 1) a1 = __builtin_amdgcn_mfma_f32_32x32x16_bf16(a, b, a1, 0, 0, 0);
                        else               a0 = __builtin_amdgcn_mfma_f32_32x32x16_bf16(a, b, a0, 0, 0, 0);
                    }
                }
                if (k >= 1) poll1(flags, d, (unsigned)k, l);
                hcell_c_lds((const char*)(hb + rb + (size_t)d*CELL64 + hoff),
                            ldsrow_hh, rot, 1024, a0, a1);
                if (k >= 3) poll2c(flags, 2, 3, (unsigned)(k - 2), l);   // WAR
                act_store<true>(a0, a1, xpa, xpb, unitg, wm, l, creg, hreg,
                                hw + (size_t)wbuf*4*CELL64 + (size_t)d*CELL64);
                asm volatile("s_waitcnt vmcnt(0)" ::: "memory");
                if (l == 0) HSTORE32(myflag, (unsigned)(k + 1));
            }
        } else {
            if (k >= 1) {
                f32x16 a0, a1;
#pragma unroll
                for (int r = 0; r < 16; ++r) { a0[r] = bias; a1[r] = 0.f; }
                if (k >= 2) poll1(flags, 2 + d, (unsigned)(k - 1), l);
                hcell_c_reg((const char*)(hb + rb + (size_t)(2+d)*CELL64 + hoff),
                            wh, a0, a1);
                poll2c(flags, 0, 1, (unsigned)k, l);
                hcell_c_lds((const char*)(hb + rb + (size_t)0*CELL64 + hoff),
                            ldsrow_ih, rot, 2048, a0, a1);
                hcell_c_lds((const char*)(hb + rb + (size_t)1*CELL64 + hoff),
                            ldsrow_ih, rot + 1024, 2048, a0, a1);
                act_store<false>(a0, a1, zero8, zero8, unitg, wm, l, creg, hreg,
                                 hw + (size_t)wbuf*4*CELL64 + (size_t)(2+d)*CELL64);
                asm volatile("s_waitcnt vmcnt(0)" ::: "memory");
                if (l == 0) HSTORE32(myflag, (unsigned)k);
            }
        }
    }

    // final c + h write-out in PLAIN layout
    {
        float*          cc = cbuf   + (size_t)mycell * HS;
        unsigned short* hh = hplain + (size_t)mycell * HS;
        const int g = l & 3, hi = l >> 5;
#pragma unroll
        for (int q = 0; q < 4; ++q) {
            int row = 32*wm + g + 8*q + 4*hi;
            cc[(size_t)row * 512 + unitg] = creg[q];
            hh[(size_t)row * 512 + unitg] = f2bf(hreg[q]);
        }
    }
}

// ---------------------------------------------------------------------------
// Head (fp32 VALU; z from plain-layout final h/c)
// ---------------------------------------------------------------------------
__global__ __launch_bounds__(256) void head_kernel(
    const unsigned short* __restrict__ hplain,
    const float* __restrict__ cbuf,
    const float* __restrict__ eps,
    const float* __restrict__ Wmu,  const float* __restrict__ bmu,
    const float* __restrict__ Wvar, const float* __restrict__ bvar,
    float* __restrict__ out)
{
    const int tid = threadIdx.x;
    const int b   = tid & 63;
    const int i   = blockIdx.x * 4 + (tid >> 6);

    __shared__ float zs[KT][B + 1];

    float amu = 0.f, alv = 0.f;
    const float* wm = Wmu  + (size_t)i * ZDIM;
    const float* wv = Wvar + (size_t)i * ZDIM;

    for (int k0 = 0; k0 < ZDIM; k0 += KT) {
        __syncthreads();
        for (int idx = tid; idx < (B * KT) / 4; idx += 256) {
            int bb  = idx / (KT / 4);
            int kq4 = (idx % (KT / 4)) * 4;
            int zk  = k0 + kq4;
            int cell = zk >> 10;
            int m    = zk & 1023;
            float4 v;
            if (m < H) {
                const unsigned short* hs = hplain + (size_t)cell * HS + (size_t)bb * H + m;
                v.x = bf2f(hs[0]); v.y = bf2f(hs[1]); v.z = bf2f(hs[2]); v.w = bf2f(hs[3]);
            } else {
                v = *(const float4*)(cbuf + (size_t)cell * HS + (size_t)bb * H + (m - H));
            }
            zs[kq4 + 0][bb] = v.x; zs[kq4 + 1][bb] = v.y;
            zs[kq4 + 2][bb] = v.z; zs[kq4 + 3][bb] = v.w;
        }
        __syncthreads();
        #pragma unroll
        for (int kk = 0; kk < KT; kk += 4) {
            float4 a = *(const float4*)(wm + k0 + kk);
            float4 c = *(const float4*)(wv + k0 + kk);
            float z0 = zs[kk + 0][b], z1 = zs[kk + 1][b];
            float z2 = zs[kk + 2][b], z3 = zs[kk + 3][b];
            amu += a.x * z0 + a.y * z1 + a.z * z2 + a.w * z3;
            alv += c.x * z0 + c.y * z1 + c.z * z2 + c.w * z3;
        }
    }
    float mu = amu + bmu[i];
    float lv = alv + bvar[i];
    out[(size_t)b * ZDIM + i] = mu + eps[(size_t)b * ZDIM + i] * __expf(0.5f * lv);
}

// ---------------------------------------------------------------------------
extern "C" void kernel_launch(void* const* d_in, const int* in_sizes, int n_in,
                              void* d_out, int out_size, void* d_ws, size_t ws_size,
                              hipStream_t stream) {
    const float* input = (const float*)d_in[0];
    const float* eps   = (const float*)d_in[1];
    const float* w_ih0 = (const float*)d_in[2];
    const float* w_hh0 = (const float*)d_in[3];
    const float* b_ih0 = (const float*)d_in[4];
    const float* b_hh0 = (const float*)d_in[5];
    const float* w_ih1 = (const float*)d_in[6];
    const float* w_hh1 = (const float*)d_in[7];
    const float* b_ih1 = (const float*)d_in[8];
    const float* b_hh1 = (const float*)d_in[9];
    const float* W_mu  = (const float*)d_in[10];
    const float* b_mu  = (const float*)d_in[11];
    const float* W_var = (const float*)d_in[12];
    const float* b_var = (const float*)d_in[13];
    float* out = (float*)d_out;

    uint8_t* base = (uint8_t*)d_ws;
    size_t off = 0;
    auto alloc = [&](size_t bytes) -> void* {
        void* p = base + off;
        off += (bytes + 255) & ~(size_t)255;
        return p;
    };
    unsigned short* xb   = (unsigned short*)alloc((size_t)TSTEPS * B * E * 2);
    unsigned short* w0p  = (unsigned short*)alloc((size_t)2 * 2048 * E * 2);
    unsigned short* wh0p = (unsigned short*)alloc((size_t)2 * 2048 * H * 2);
    unsigned short* w1p  = (unsigned short*)alloc((size_t)2 * 2048 * 1024 * 2);
    unsigned short* wh1p = (unsigned short*)alloc((size_t)2 * 2048 * H * 2);
    float* b0p = (float*)alloc(2 * 2048 * 4);
    float* b1p = (float*)alloc(2 * 2048 * 4);
    unsigned* flags      = (unsigned*)alloc(4 * 128 * 64);            // 32KB
    unsigned short* hbuf = (unsigned short*)alloc((size_t)3 * 4 * HS * 2);
    float* cbuf          = (float*)alloc((size_t)4 * HS * 4);
    unsigned short* hplain = (unsigned short*)alloc((size_t)4 * HS * 2);
    size_t off_noxp = off;
    unsigned short* xp   = (unsigned short*)alloc((size_t)TSTEPS * 2 * 2048 * B * 2); // 134MB
    const bool XPRE = (ws_size >= off);
    (void)off_noxp;

    // zero flags + h (3 bufs)
    hipMemsetAsync(flags, 0, 4 * 128 * 64 + (size_t)3 * 4 * HS * 2, stream);

    conv_x_kernel<<<(TSTEPS * B * E / 8 + 255) / 256, 256, 0, stream>>>(input, xb, TSTEPS * B * E / 8);
    repack_w_kernel<<<(2 * 2048 * (E / 8) + 255) / 256, 256, 0, stream>>>(w_ih0, w0p, E);
    repack_w_kernel<<<(2 * 2048 * (H / 8) + 255) / 256, 256, 0, stream>>>(w_hh0, wh0p, H);
    repack_w_kernel<<<(2 * 2048 * (1024 / 8) + 255) / 256, 256, 0, stream>>>(w_ih1, w1p, 1024);
    repack_w_kernel<<<(2 * 2048 * (H / 8) + 255) / 256, 256, 0, stream>>>(w_hh1, wh1p, H);
    pack_bias_kernel<<<16, 256, 0, stream>>>(b_ih0, b_hh0, b0p);
    pack_bias_kernel<<<16, 256, 0, stream>>>(b_ih1, b_hh1, b1p);

    const size_t lds_persist = 144 * 1024;
    if (XPRE) {
        const size_t lds_xp = 84 * 1024;
        hipFuncSetAttribute((const void*)xproj_kernel,
                            hipFuncAttributeMaxDynamicSharedMemorySize, (int)lds_xp);
        xproj_kernel<<<dim3(64, 4), 256, lds_xp, stream>>>(xb, w0p, xp);
        hipFuncSetAttribute((const void*)persist_kernel<1>,
                            hipFuncAttributeMaxDynamicSharedMemorySize, (int)lds_persist);
        persist_kernel<1><<<128, 256, lds_persist, stream>>>(
            xb, w0p, wh0p, w1p, wh1p, b0p, b1p, xp, hbuf, cbuf, hplain, flags);
    } else {
        hipFuncSetAttribute((const void*)persist_kernel<0>,
                            hipFuncAttributeMaxDynamicSharedMemorySize, (int)lds_persist);
        persist_kernel<0><<<128, 256, lds_persist, stream>>>(
            xb, w0p, wh0p, w1p, wh1p, b0p, b1p, xp, hbuf, cbuf, hplain, flags);
    }

    head_kernel<<<ZDIM / 4, 256, 0, stream>>>(hplain, cbuf, eps, W_mu, b_mu, W_var, b_var, out);
}

// Round 10
// 3244.932 us; speedup vs baseline: 2.5296x; 1.0163x over previous
//
#include <hip/hip_runtime.h>
#include <hip/hip_bf16.h>
#include <cstddef>
#include <cstdint>

#define B     64
#define S     256
#define E     640
#define H     512
#define TSTEPS (S - 1)       // 255
#define ZDIM  4096
#define KT    64
#define HS    (B * H)        // elems per state cell (32768)
#define CELL64 8192          // u64 units per h cell (64*512*2B / 8)
#define NBUF  4              // h rotation depth

typedef __attribute__((ext_vector_type(8)))  __bf16 bf16x8;
typedef __attribute__((ext_vector_type(16))) float  f32x16;
typedef unsigned long long ull;

__device__ __forceinline__ float sigf(float x) { return 1.0f / (1.0f + __expf(-x)); }
__device__ __forceinline__ float tanhfast(float x) { return 1.0f - 2.0f / (__expf(2.0f * x) + 1.0f); }

__device__ __forceinline__ unsigned short f2bf(float f) {
    union { float f; unsigned u; } x; x.f = f;
    unsigned r = x.u + 0x7fffu + ((x.u >> 16) & 1u);   // RNE
    return (unsigned short)(r >> 16);
}
__device__ __forceinline__ float bf2f(unsigned short u) {
    union { unsigned u; float f; } x; x.u = ((unsigned)u) << 16;
    return x.f;
}
__device__ __forceinline__ unsigned pk2(float a, float b) {
    return (unsigned)f2bf(a) | ((unsigned)f2bf(b) << 16);
}

#define HSTORE64(p, v) __hip_atomic_store((p), (v), __ATOMIC_RELAXED, __HIP_MEMORY_SCOPE_AGENT)
#define HSTORE32(p, v) __hip_atomic_store((p), (v), __ATOMIC_RELAXED, __HIP_MEMORY_SCOPE_AGENT)

// Coherence-point plain loads (bypass L1+L2), pipelined; drain with cwait0().
__device__ __forceinline__ uint4 cld16(const void* p) {
    uint4 v;
    asm volatile("global_load_dwordx4 %0, %1, off sc0 sc1"
                 : "=v"(v) : "v"(p) : "memory");
    return v;
}
__device__ __forceinline__ unsigned ldf(const unsigned* p) {
    unsigned v;
    asm volatile("global_load_dword %0, %1, off sc0 sc1"
                 : "=v"(v) : "v"(p) : "memory");
    return v;
}
__device__ __forceinline__ void cwait0() {
    asm volatile("s_waitcnt vmcnt(0)" ::: "memory");
    __builtin_amdgcn_sched_barrier(0);
}
__device__ __forceinline__ bf16x8 u2b(uint4 u) {
    union { uint4 u; bf16x8 b; } x; x.u = u; return x.b;
}

// h-cell fragment layout (u64 granules): idx = wm*4096 + m*128 + khalf*64 + row*2 + plane

// ---------------------------------------------------------------------------
// Prep kernels
// ---------------------------------------------------------------------------
__global__ __launch_bounds__(256) void conv_x_kernel(
    const float* __restrict__ in, unsigned short* __restrict__ out, int n8)
{
    int i = blockIdx.x * 256 + threadIdx.x;
    if (i >= n8) return;
    const float4* p = (const float4*)(in + (size_t)i * 8);
    float4 a = p[0], b = p[1];
    unsigned short* o = out + (size_t)i * 8;
    o[0] = f2bf(a.x); o[1] = f2bf(a.y); o[2] = f2bf(a.z); o[3] = f2bf(a.w);
    o[4] = f2bf(b.x); o[5] = f2bf(b.y); o[6] = f2bf(b.z); o[7] = f2bf(b.w);
}

__global__ __launch_bounds__(256) void repack_w_kernel(
    const float* __restrict__ in, unsigned short* __restrict__ out, int K)
{
    int kc = K / 8;
    int i = blockIdx.x * 256 + threadIdx.x;
    if (i >= 2 * 2048 * kc) return;
    int k8 = i % kc;
    int n  = (i / kc) & 2047;
    int d  = i / (kc * 2048);
    int srow = (n & 3) * 512 + (n >> 2);
    const float* src = in + ((size_t)d * 2048 + srow) * K + (size_t)k8 * 8;
    unsigned short* dst = out + ((size_t)d * 2048 + n) * K + (size_t)k8 * 8;
    #pragma unroll
    for (int q = 0; q < 8; ++q) dst[q] = f2bf(src[q]);
}

__global__ __launch_bounds__(256) void pack_bias_kernel(
    const float* __restrict__ bih, const float* __restrict__ bhh, float* __restrict__ out)
{
    int i = blockIdx.x * 256 + threadIdx.x;   // 4096
    if (i >= 4096) return;
    int d = i >> 11, n = i & 2047;
    int s = d * 2048 + (n & 3) * 512 + (n >> 2);
    out[i] = bih[s] + bhh[s];
}

// ---------------------------------------------------------------------------
// x-projection GEMM (unchanged from r8)
// ---------------------------------------------------------------------------
__global__ __launch_bounds__(256) void xproj_kernel(
    const unsigned short* __restrict__ xb,
    const unsigned short* __restrict__ w0p,
    unsigned short* __restrict__ xp)
{
    extern __shared__ __align__(16) char lds[];
    const int tid = threadIdx.x;
    const int l   = tid & 63;
    const int w   = tid >> 6;
    const int wm  = w & 1, wn = w >> 1;
    const int d   = blockIdx.x >> 5;
    const int n0  = (blockIdx.x & 31) * 64;

    for (int idx = tid; idx < 64 * 80; idx += 256) {
        int r = idx / 80, k8 = idx % 80;
        bf16x8 v = *(const bf16x8*)(w0p + ((size_t)d*2048 + n0 + r)*640 + (size_t)k8*8);
        int o = k8*16 + r*16; o -= (o >= 1280) ? 1280 : 0;
        *(bf16x8*)(lds + r*1280 + o) = v;
    }
    __syncthreads();

    const int lrow  = wn * 32 + (l & 31);
    const int khalf = l >> 5;
    const char* ldsrow = lds + (size_t)lrow * 1280;
    const int rot = lrow * 16 + khalf * 16;
    const int t0 = blockIdx.y * 64;
    const int t1 = (t0 + 64 < TSTEPS) ? (t0 + 64) : TSTEPS;

    for (int t = t0; t < t1; ++t) {
        f32x16 a0, a1;
#pragma unroll
        for (int r = 0; r < 16; ++r) { a0[r] = 0.f; a1[r] = 0.f; }
        const unsigned short* Ax = xb + ((size_t)t*B + wm*32 + (l & 31))*E + khalf*8;
#pragma unroll 8
        for (int k0 = 0; k0 < E; k0 += 16) {
            bf16x8 a = *(const bf16x8*)(Ax + k0);
            int o = k0*2 + rot; o -= (o >= 1280) ? 1280 : 0;
            bf16x8 b = *(const bf16x8*)(ldsrow + o);
            if ((k0 >> 4) & 1) a1 = __builtin_amdgcn_mfma_f32_32x32x16_bf16(a, b, a1, 0, 0, 0);
            else               a0 = __builtin_amdgcn_mfma_f32_32x32x16_bf16(a, b, a0, 0, 0, 0);
        }
        size_t base = ((((size_t)t*2 + d)*64 + (n0 >> 5) + wn)*2 + wm)*1024 + (size_t)l*16;
        unsigned short* dst = xp + base;
        uint4 o0, o1;
        o0.x = pk2(a0[0]+a1[0],  a0[1]+a1[1]);
        o0.y = pk2(a0[2]+a1[2],  a0[3]+a1[3]);
        o0.z = pk2(a0[4]+a1[4],  a0[5]+a1[5]);
        o0.w = pk2(a0[6]+a1[6],  a0[7]+a1[7]);
        o1.x = pk2(a0[8]+a1[8],  a0[9]+a1[9]);
        o1.y = pk2(a0[10]+a1[10], a0[11]+a1[11]);
        o1.z = pk2(a0[12]+a1[12], a0[13]+a1[13]);
        o1.w = pk2(a0[14]+a1[14], a0[15]+a1[15]);
        *(uint4*)dst       = o0;
        *(uint4*)(dst + 8) = o1;
    }
}

// ---------------------------------------------------------------------------
// Batched polls (flags[4][128] slots x 64B). All flag loads issue back-to-back
// (plain sc0 sc1 -> coherence point), ONE vmcnt drain per iteration.
// ---------------------------------------------------------------------------
// L0: own cell d >= traw  AND  cells 2,3 >= twar (WAR; twar=0 trivially true)
__device__ __forceinline__ void poll_l0(const unsigned* flags, int d,
                                        unsigned traw, unsigned twar, int l)
{
    const unsigned* pd = flags + (size_t)(d*128 + l) * 16;
    const unsigned* p2 = flags + (size_t)(2*128 + l) * 16;
    const unsigned* p3 = flags + (size_t)(3*128 + l) * 16;
    for (;;) {
        unsigned a0 = ldf(pd), a1 = ldf(pd + 64*16);
        unsigned b0 = ldf(p2), b1 = ldf(p2 + 64*16);
        unsigned c0 = ldf(p3), c1 = ldf(p3 + 64*16);
        cwait0();
        unsigned ra = a0 < a1 ? a0 : a1;
        unsigned wb = b0 < b1 ? b0 : b1;
        unsigned wc = c0 < c1 ? c0 : c1;
        unsigned ww = wb < wc ? wb : wc;
        if (__all((int)(ra >= traw && ww >= twar))) break;
        __builtin_amdgcn_s_sleep(1);
    }
}
// single cell >= tgt
__device__ __forceinline__ void poll_1c(const unsigned* flags, int cell,
                                        unsigned tgt, int l)
{
    const unsigned* p0 = flags + (size_t)(cell*128 + l) * 16;
    for (;;) {
        unsigned a0 = ldf(p0), a1 = ldf(p0 + 64*16);
        cwait0();
        unsigned v = a0 < a1 ? a0 : a1;
        if (__all((int)(v >= tgt))) break;
        __builtin_amdgcn_s_sleep(1);
    }
}
// cells ca,cb >= tgt
__device__ __forceinline__ void poll_2c(const unsigned* flags, int ca, int cb,
                                        unsigned tgt, int l)
{
    const unsigned* p0 = flags + (size_t)(ca*128 + l) * 16;
    const unsigned* p1 = flags + (size_t)(cb*128 + l) * 16;
    for (;;) {
        unsigned a0 = ldf(p0), a1 = ldf(p0 + 64*16);
        unsigned b0 = ldf(p1), b1 = ldf(p1 + 64*16);
        cwait0();
        unsigned v = a0 < a1 ? a0 : a1;
        unsigned u = b0 < b1 ? b0 : b1;
        v = v < u ? v : u;
        if (__all((int)(v >= tgt))) break;
        __builtin_amdgcn_s_sleep(1);
    }
}

// ---------------------------------------------------------------------------
// Coherent h-cell consumers (32 x 16B pipelined loads, one drain)
// hp byte base pre-offset: cell + wm*4096 + khalf*64 + (l&31)*2  (u64 units)
// ---------------------------------------------------------------------------
__device__ __forceinline__ void hcell_c_lds(const void* hp, const char* ldsrow,
    int rotofs, int wrapB, f32x16& a0, f32x16& a1)
{
    uint4 hv[32];
#pragma unroll
    for (int m = 0; m < 32; ++m)
        hv[m] = cld16((const char*)hp + (size_t)m * 1024);
    cwait0();
#pragma unroll
    for (int m = 0; m < 32; ++m) {
        int o = m*32 + rotofs; o -= (o >= wrapB) ? wrapB : 0;
        bf16x8 b = *(const bf16x8*)(ldsrow + o);
        bf16x8 a = u2b(hv[m]);
        if (m & 1) a1 = __builtin_amdgcn_mfma_f32_32x32x16_bf16(a, b, a1, 0, 0, 0);
        else       a0 = __builtin_amdgcn_mfma_f32_32x32x16_bf16(a, b, a0, 0, 0, 0);
    }
}

__device__ __forceinline__ void hcell_c_reg(const void* hp, const bf16x8* wh,
    f32x16& a0, f32x16& a1)
{
    uint4 hv[32];
#pragma unroll
    for (int m = 0; m < 32; ++m)
        hv[m] = cld16((const char*)hp + (size_t)m * 1024);
    cwait0();
#pragma unroll
    for (int m = 0; m < 32; ++m) {
        bf16x8 a = u2b(hv[m]);
        if (m & 1) a1 = __builtin_amdgcn_mfma_f32_32x32x16_bf16(a, wh[m], a1, 0, 0, 0);
        else       a0 = __builtin_amdgcn_mfma_f32_32x32x16_bf16(a, wh[m], a0, 0, 0, 0);
    }
}

// ---------------------------------------------------------------------------
// Activation + c/h-in-registers + coalesced fragment-order h store
// ---------------------------------------------------------------------------
template<bool XADD>
__device__ __forceinline__ void act_store(
    const f32x16& a0, const f32x16& a1, bf16x8 xpa, bf16x8 xpb,
    int unitg, int wm, int l, float* creg, float* hreg, ull* hq_cell)
{
    const int g  = l & 3;
    const int hi = l >> 5;
    union { bf16x8 v; unsigned short s[8]; } ua, ub;
    ua.v = xpa; ub.v = xpb;
    float gi[4], gf[4], gg[4], go[4];
#pragma unroll
    for (int r = 0; r < 16; ++r) {
        float v0 = a0[r] + a1[r];
        if (XADD) v0 += bf2f((r < 8) ? ua.s[r] : ub.s[r - 8]);
        float v1 = __shfl_xor(v0, 1);
        float v2 = __shfl_xor(v0, 2);
        float v3 = __shfl_xor(v0, 3);
        float pv[4] = {v0, v1, v2, v3};
        const int rg = r & 3, q = r >> 2;
        if (g == rg) { gi[q] = pv[rg^0]; gf[q] = pv[rg^1]; gg[q] = pv[rg^2]; go[q] = pv[rg^3]; }
    }
    const int ubase = unitg & ~3;
    ull* dst = hq_cell + wm*4096 + (ubase >> 4)*128 + ((ubase >> 3) & 1)*64
                       + ((ubase >> 2) & 1);
#pragma unroll
    for (int q = 0; q < 4; ++q) {
        int rl = g + 8*q + 4*hi;
        float cold = creg[q];
        float cnew = sigf(gf[q]) * cold + sigf(gi[q]) * tanhfast(gg[q]);
        float hnew = sigf(go[q]) * tanhfast(cnew);
        creg[q] = cnew;
        hreg[q] = hnew;
        unsigned m  = f2bf(hnew);
        unsigned o1 = __shfl_xor(m, 4);
        unsigned d0 = (unitg & 1) ? ((m << 16) | o1) : ((o1 << 16) | m);
        unsigned o2 = __shfl_xor(d0, 8);
        ull q64 = (unitg & 2) ? (((ull)d0 << 32) | (ull)o2) : (((ull)o2 << 32) | (ull)d0);
        if ((l & 12) == 0)
            HSTORE64(dst + rl*2, q64);
    }
}

// ---------------------------------------------------------------------------
// Persistent recurrence. 128 blocks x 256 thr, 144KB dyn LDS.
// bid<64: L0; else L1. Sync: per-wave flag slots (batched polls);
// NBUF=4 h rotation -> WAR target k-3 (3 steps of slack).
// ---------------------------------------------------------------------------
template<int XPRE>
__global__ __launch_bounds__(256, 1) void persist_kernel(
    const unsigned short* __restrict__ xb,
    const unsigned short* __restrict__ w0p,
    const unsigned short* __restrict__ wh0p,
    const unsigned short* __restrict__ w1p,
    const unsigned short* __restrict__ wh1p,
    const float* __restrict__ b0p,
    const float* __restrict__ b1p,
    const unsigned short* __restrict__ xp,
    unsigned short* __restrict__ hbuf,   // (NBUF,4 cells) fragment-order bf16
    float* __restrict__ cbuf,
    unsigned short* __restrict__ hplain,
    unsigned* __restrict__ flags)        // 4 cells x 128 slots x 64B
{
    extern __shared__ __align__(16) char lds[];
    const int tid = threadIdx.x;
    const int l   = tid & 63;
    const int w   = tid >> 6;
    const int wm  = w & 1, wn = w >> 1;
    const int bid = blockIdx.x;
    const bool isL1 = bid >= 64;
    const int g2 = bid & 63;
    const int d  = g2 >> 5;
    const int n0 = (g2 & 31) * 64;
    const int myslot = g2 & 31;
    const int lrow  = wn * 32 + (l & 31);
    const int khalf = l >> 5;
    const int HHOFF = 64 * 1280;

    // ---- stage weights into LDS --------------------------------------------
    if (!isL1) {
        if (!XPRE) {
            for (int idx = tid; idx < 64 * 80; idx += 256) {
                int r = idx / 80, k8 = idx % 80;
                bf16x8 v = *(const bf16x8*)(w0p + ((size_t)d*2048 + n0 + r)*640 + (size_t)k8*8);
                int o = k8*16 + r*16; o -= (o >= 1280) ? 1280 : 0;
                *(bf16x8*)(lds + r*1280 + o) = v;
            }
        }
        const int hb0 = XPRE ? 0 : HHOFF;
        for (int idx = tid; idx < 64 * 64; idx += 256) {
            int r = idx / 64, k8 = idx % 64;
            bf16x8 v = *(const bf16x8*)(wh0p + ((size_t)d*2048 + n0 + r)*512 + (size_t)k8*8);
            int o = k8*16 + r*16; o -= (o >= 1024) ? 1024 : 0;
            *(bf16x8*)(lds + hb0 + r*1024 + o) = v;
        }
    } else {
        for (int idx = tid; idx < 64 * 128; idx += 256) {
            int r = idx / 128, k8 = idx % 128;
            bf16x8 v = *(const bf16x8*)(w1p + ((size_t)d*2048 + n0 + r)*1024 + (size_t)k8*8);
            int o = k8*16 + r*16; o -= (o >= 2048) ? 2048 : 0;
            *(bf16x8*)(lds + r*2048 + o) = v;
        }
    }
    __syncthreads();

    const float bias = (isL1 ? b1p : b0p)[d*2048 + n0 + lrow];
    const char* ldsrow_ih = lds + (size_t)lrow * (isL1 ? 2048 : 1280);
    const char* ldsrow_hh = lds + (XPRE ? 0 : HHOFF) + (size_t)lrow * 1024;
    const int rot = lrow * 16 + khalf * 16;
    const int unitg = ((n0 + lrow) >> 2);
    const int hoff  = wm*4096 + khalf*64 + (l & 31)*2;
    const int arow  = wm * 32 + (l & 31);
    float creg[4] = {0.f, 0.f, 0.f, 0.f};
    float hreg[4] = {0.f, 0.f, 0.f, 0.f};
    const ull* hb = (const ull*)hbuf;
    ull*       hw = (ull*)hbuf;
    const int mycell = isL1 ? (2 + d) : d;
    unsigned* myflag = flags + (size_t)(mycell*128 + myslot*4 + w) * 16;
    bf16x8 zero8 = {};

    // L1: preload whh B-fragments into registers
    bf16x8 wh[32];
    if (isL1) {
        const unsigned short* whl = wh1p + ((size_t)d*2048 + n0 + lrow)*512 + khalf*8;
#pragma unroll
        for (int m = 0; m < 32; ++m) wh[m] = *(const bf16x8*)(whl + m*16);
    }

    for (int k = 0; k <= TSTEPS; ++k) {
        const int rbuf = k % NBUF, wbuf = (k + 1) % NBUF;
        const size_t rb = (size_t)rbuf * 4 * CELL64;
        const size_t wb = (size_t)wbuf * 4 * CELL64;
        if (!isL1) {
            if (k < TSTEPS) {
                f32x16 a0, a1;
#pragma unroll
                for (int r = 0; r < 16; ++r) { a0[r] = bias; a1[r] = 0.f; }
                bf16x8 xpa = zero8, xpb = zero8;
                if (XPRE) {
                    size_t base = ((((size_t)k*2 + d)*64 + (n0 >> 5) + wn)*2 + wm)*1024
                                  + (size_t)l*16;
                    xpa = *(const bf16x8*)(xp + base);
                    xpb = *(const bf16x8*)(xp + base + 8);
                } else {
                    const unsigned short* Ax = xb + (size_t)k*B*E + (size_t)arow*E + khalf*8;
#pragma unroll 8
                    for (int k0 = 0; k0 < E; k0 += 16) {
                        bf16x8 a = *(const bf16x8*)(Ax + k0);
                        int o = k0*2 + rot; o -= (o >= 1280) ? 1280 : 0;
                        bf16x8 b = *(const bf16x8*)(ldsrow_ih + o);
                        if ((k0 >> 4) & 1) a1 = __builtin_amdgcn_mfma_f32_32x32x16_bf16(a, b, a1, 0, 0, 0);
                        else               a0 = __builtin_amdgcn_mfma_f32_32x32x16_bf16(a, b, a0, 0, 0, 0);
                    }
                }
                // merged RAW (own cell >= k) + WAR (L1 cells >= k-3); one RT
                if (k >= 1)
                    poll_l0(flags, d, (unsigned)k,
                            (k >= 3) ? (unsigned)(k - 3) : 0u, l);
                hcell_c_lds((const char*)(hb + rb + (size_t)d*CELL64 + hoff),
                            ldsrow_hh, rot, 1024, a0, a1);
                act_store<true>(a0, a1, xpa, xpb, unitg, wm, l, creg, hreg,
                                hw + wb + (size_t)d*CELL64);
                asm volatile("s_waitcnt vmcnt(0)" ::: "memory");
                if (l == 0) HSTORE32(myflag, (unsigned)(k + 1));
            }
        } else {
            if (k >= 1) {
                f32x16 a0, a1;
#pragma unroll
                for (int r = 0; r < 16; ++r) { a0[r] = bias; a1[r] = 0.f; }
                if (k >= 2) poll_1c(flags, 2 + d, (unsigned)(k - 1), l);
                hcell_c_reg((const char*)(hb + rb + (size_t)(2+d)*CELL64 + hoff),
                            wh, a0, a1);
                poll_2c(flags, 0, 1, (unsigned)k, l);
                hcell_c_lds((const char*)(hb + rb + (size_t)0*CELL64 + hoff),
                            ldsrow_ih, rot, 2048, a0, a1);
                hcell_c_lds((const char*)(hb + rb + (size_t)1*CELL64 + hoff),
                            ldsrow_ih, rot + 1024, 2048, a0, a1);
                act_store<false>(a0, a1, zero8, zero8, unitg, wm, l, creg, hreg,
                                 hw + wb + (size_t)(2+d)*CELL64);
                asm volatile("s_waitcnt vmcnt(0)" ::: "memory");
                if (l == 0) HSTORE32(myflag, (unsigned)k);
            }
        }
    }

    // final c + h write-out in PLAIN layout (h kept in registers)
    {
        float*          cc = cbuf   + (size_t)mycell * HS;
        unsigned short* hh = hplain + (size_t)mycell * HS;
        const int g = l & 3, hi = l >> 5;
#pragma unroll
        for (int q = 0; q < 4; ++q) {
            int row = 32*wm + g + 8*q + 4*hi;
            cc[(size_t)row * 512 + unitg] = creg[q];
            hh[(size_t)row * 512 + unitg] = f2bf(hreg[q]);
        }
    }
}

// ---------------------------------------------------------------------------
// Head (fp32 VALU; z from plain-layout final h/c)
// ---------------------------------------------------------------------------
__global__ __launch_bounds__(256) void head_kernel(
    const unsigned short* __restrict__ hplain,
    const float* __restrict__ cbuf,
    const float* __restrict__ eps,
    const float* __restrict__ Wmu,  const float* __restrict__ bmu,
    const float* __restrict__ Wvar, const float* __restrict__ bvar,
    float* __restrict__ out)
{
    const int tid = threadIdx.x;
    const int b   = tid & 63;
    const int i   = blockIdx.x * 4 + (tid >> 6);

    __shared__ float zs[KT][B + 1];

    float amu = 0.f, alv = 0.f;
    const float* wm = Wmu  + (size_t)i * ZDIM;
    const float* wv = Wvar + (size_t)i * ZDIM;

    for (int k0 = 0; k0 < ZDIM; k0 += KT) {
        __syncthreads();
        for (int idx = tid; idx < (B * KT) / 4; idx += 256) {
            int bb  = idx / (KT / 4);
            int kq4 = (idx % (KT / 4)) * 4;
            int zk  = k0 + kq4;
            int cell = zk >> 10;
            int m    = zk & 1023;
            float4 v;
            if (m < H) {
                const unsigned short* hs = hplain + (size_t)cell * HS + (size_t)bb * H + m;
                v.x = bf2f(hs[0]); v.y = bf2f(hs[1]); v.z = bf2f(hs[2]); v.w = bf2f(hs[3]);
            } else {
                v = *(const float4*)(cbuf + (size_t)cell * HS + (size_t)bb * H + (m - H));
            }
            zs[kq4 + 0][bb] = v.x; zs[kq4 + 1][bb] = v.y;
            zs[kq4 + 2][bb] = v.z; zs[kq4 + 3][bb] = v.w;
        }
        __syncthreads();
        #pragma unroll
        for (int kk = 0; kk < KT; kk += 4) {
            float4 a = *(const float4*)(wm + k0 + kk);
            float4 c = *(const float4*)(wv + k0 + kk);
            float z0 = zs[kk + 0][b], z1 = zs[kk + 1][b];
            float z2 = zs[kk + 2][b], z3 = zs[kk + 3][b];
            amu += a.x * z0 + a.y * z1 + a.z * z2 + a.w * z3;
            alv += c.x * z0 + c.y * z1 + c.z * z2 + c.w * z3;
        }
    }
    float mu = amu + bmu[i];
    float lv = alv + bvar[i];
    out[(size_t)b * ZDIM + i] = mu + eps[(size_t)b * ZDIM + i] * __expf(0.5f * lv);
}

// ---------------------------------------------------------------------------
extern "C" void kernel_launch(void* const* d_in, const int* in_sizes, int n_in,
                              void* d_out, int out_size, void* d_ws, size_t ws_size,
                              hipStream_t stream) {
    const float* input = (const float*)d_in[0];
    const float* eps   = (const float*)d_in[1];
    const float* w_ih0 = (const float*)d_in[2];
    const float* w_hh0 = (const float*)d_in[3];
    const float* b_ih0 = (const float*)d_in[4];
    const float* b_hh0 = (const float*)d_in[5];
    const float* w_ih1 = (const float*)d_in[6];
    const float* w_hh1 = (const float*)d_in[7];
    const float* b_ih1 = (const float*)d_in[8];
    const float* b_hh1 = (const float*)d_in[9];
    const float* W_mu  = (const float*)d_in[10];
    const float* b_mu  = (const float*)d_in[11];
    const float* W_var = (const float*)d_in[12];
    const float* b_var = (const float*)d_in[13];
    float* out = (float*)d_out;

    uint8_t* base = (uint8_t*)d_ws;
    size_t off = 0;
    auto alloc = [&](size_t bytes) -> void* {
        void* p = base + off;
        off += (bytes + 255) & ~(size_t)255;
        return p;
    };
    unsigned short* xb   = (unsigned short*)alloc((size_t)TSTEPS * B * E * 2);
    unsigned short* w0p  = (unsigned short*)alloc((size_t)2 * 2048 * E * 2);
    unsigned short* wh0p = (unsigned short*)alloc((size_t)2 * 2048 * H * 2);
    unsigned short* w1p  = (unsigned short*)alloc((size_t)2 * 2048 * 1024 * 2);
    unsigned short* wh1p = (unsigned short*)alloc((size_t)2 * 2048 * H * 2);
    float* b0p = (float*)alloc(2 * 2048 * 4);
    float* b1p = (float*)alloc(2 * 2048 * 4);
    unsigned* flags      = (unsigned*)alloc(4 * 128 * 64);            // 32KB
    unsigned short* hbuf = (unsigned short*)alloc((size_t)NBUF * 4 * HS * 2);
    float* cbuf          = (float*)alloc((size_t)4 * HS * 4);
    unsigned short* hplain = (unsigned short*)alloc((size_t)4 * HS * 2);
    unsigned short* xp   = (unsigned short*)alloc((size_t)TSTEPS * 2 * 2048 * B * 2); // 134MB
    const bool XPRE = (ws_size >= off);

    // zero flags + h (NBUF bufs)
    hipMemsetAsync(flags, 0, 4 * 128 * 64 + (size_t)NBUF * 4 * HS * 2, stream);

    conv_x_kernel<<<(TSTEPS * B * E / 8 + 255) / 256, 256, 0, stream>>>(input, xb, TSTEPS * B * E / 8);
    repack_w_kernel<<<(2 * 2048 * (E / 8) + 255) / 256, 256, 0, stream>>>(w_ih0, w0p, E);
    repack_w_kernel<<<(2 * 2048 * (H / 8) + 255) / 256, 256, 0, stream>>>(w_hh0, wh0p, H);
    repack_w_kernel<<<(2 * 2048 * (1024 / 8) + 255) / 256, 256, 0, stream>>>(w_ih1, w1p, 1024);
    repack_w_kernel<<<(2 * 2048 * (H / 8) + 255) / 256, 256, 0, stream>>>(w_hh1, wh1p, H);
    pack_bias_kernel<<<16, 256, 0, stream>>>(b_ih0, b_hh0, b0p);
    pack_bias_kernel<<<16, 256, 0, stream>>>(b_ih1, b_hh1, b1p);

    const size_t lds_persist = 144 * 1024;
    if (XPRE) {
        const size_t lds_xp = 84 * 1024;
        hipFuncSetAttribute((const void*)xproj_kernel,
                            hipFuncAttributeMaxDynamicSharedMemorySize, (int)lds_xp);
        xproj_kernel<<<dim3(64, 4), 256, lds_xp, stream>>>(xb, w0p, xp);
        hipFuncSetAttribute((const void*)persist_kernel<1>,
                            hipFuncAttributeMaxDynamicSharedMemorySize, (int)lds_persist);
        persist_kernel<1><<<128, 256, lds_persist, stream>>>(
            xb, w0p, wh0p, w1p, wh1p, b0p, b1p, xp, hbuf, cbuf, hplain, flags);
    } else {
        hipFuncSetAttribute((const void*)persist_kernel<0>,
                            hipFuncAttributeMaxDynamicSharedMemorySize, (int)lds_persist);
        persist_kernel<0><<<128, 256, lds_persist, stream>>>(
            xb, w0p, wh0p, w1p, wh1p, b0p, b1p, xp, hbuf, cbuf, hplain, flags);
    }

    head_kernel<<<ZDIM / 4, 256, 0, stream>>>(hplain, cbuf, eps, W_mu, b_mu, W_var, b_var, out);
}